// Round 15
// baseline (3122.666 us; speedup 1.0000x reference)
//
#include <hip/hip_runtime.h>
#include <math.h>

#define M2 4225
#define NTRAIN 100000
#define NTEST 50000
#define CGITERS 30
#define TWO_PI_D 6.283185307179586476925287
#define TPI32 6.28318530717958647692f

// ---- float offsets ----
#define F_H 0
#define F_RS 1
#define F_CNT 2         // software-barrier counter (unsigned)
#define F_GEN 3         // software-barrier generation (unsigned)
// mm encoded uints at floats 4..7
#define F_WS 8          // 4225
#define F_RHS 4234      // 8450 (float2)
#define F_X 12684
#define F_R 21134
#define F_P 29584
#define F_AP 38034
#define F_PB 46484      // 4225 products
#define F_VF 50710      // 129*129 float2 = 33282
#define F_VHAT 83992    // 33282
#define F_PROD 117274   // 33282 (end 150556)
// ---- double offsets ----
#define D_VPART 125330  // 128*16770
#define D_FKPART 2271890 // 128*4290 (end 2821010 dbl = 22.6MB)

#define NCHUNK 128
#define PTSB2 782
#define VHALF 8385
#define VH2 16770
#define FKHALF 2145
#define FH2 4290
#define NBLK 129u

__device__ __forceinline__ unsigned fkey(float f){
  unsigned u = __float_as_uint(f);
  return (u & 0x80000000u) ? ~u : (u | 0x80000000u);
}
__device__ __forceinline__ float fdec(unsigned k){
  unsigned u = (k & 0x80000000u) ? (k & 0x7fffffffu) : ~k;
  return __uint_as_float(u);
}

__global__ void k_init(unsigned* mm){
  if (threadIdx.x == 0){
    mm[0] = 0xFFFFFFFFu; mm[1] = 0u; mm[2] = 0xFFFFFFFFu; mm[3] = 0u;
  }
}

__global__ void k_minmax(const float* __restrict__ x, const float* __restrict__ xn,
                         unsigned* __restrict__ mm){
  int tid = blockIdx.x * blockDim.x + threadIdx.x;
  int str = gridDim.x * blockDim.x;
  float mn0 = 1e30f, mx0 = -1e30f, mn1 = 1e30f, mx1 = -1e30f;
  const float2* a = (const float2*)x;
  for (int i = tid; i < NTRAIN; i += str){
    float2 v = a[i];
    mn0 = fminf(mn0, v.x); mx0 = fmaxf(mx0, v.x);
    mn1 = fminf(mn1, v.y); mx1 = fmaxf(mx1, v.y);
  }
  const float2* b = (const float2*)xn;
  for (int i = tid; i < NTEST; i += str){
    float2 v = b[i];
    mn0 = fminf(mn0, v.x); mx0 = fmaxf(mx0, v.x);
    mn1 = fminf(mn1, v.y); mx1 = fmaxf(mx1, v.y);
  }
  for (int off = 32; off; off >>= 1){
    mn0 = fminf(mn0, __shfl_xor(mn0, off, 64));
    mx0 = fmaxf(mx0, __shfl_xor(mx0, off, 64));
    mn1 = fminf(mn1, __shfl_xor(mn1, off, 64));
    mx1 = fmaxf(mx1, __shfl_xor(mx1, off, 64));
  }
  if ((threadIdx.x & 63) == 0){
    atomicMin(&mm[0], fkey(mn0)); atomicMax(&mm[1], fkey(mx0));
    atomicMin(&mm[2], fkey(mn1)); atomicMax(&mm[3], fkey(mx1));
  }
}

__global__ void k_setup(float* __restrict__ wsf){
  const unsigned* mm = (const unsigned*)(wsf + 4);
  float mn0 = fdec(mm[0]), mx0 = fdec(mm[1]);
  float mn1 = fdec(mm[2]), mx1 = fdec(mm[3]);
  float d0 = __fsub_rn(mx0, mn0), d1 = __fsub_rn(mx1, mn1);
  float L = fmaxf(d0, d1);
  if (L <= 1e-9f) L = 1.0f;
  float hf = __fdiv_rn(1.0f, L);
  if (threadIdx.x == 0) wsf[F_H] = hf;
  const float c0f = (float)(TWO_PI_D * 0.01);
  const float c1f = (float)(-2.0 * 9.869604401089358618834 * 0.01);
  float h2f = __fmul_rn(hf, hf);
  for (int e = threadIdx.x; e < M2; e += blockDim.x){
    int r = e / 65, c = e - r * 65;
    float xi0 = __fmul_rn(hf, (float)(r - 32));
    float xi1 = __fmul_rn(hf, (float)(c - 32));
    float sq = __fadd_rn(__fmul_rn(xi0, xi0), __fmul_rn(xi1, xi1));
    float spec = __fmul_rn(c0f, expf(__fmul_rn(c1f, sq)));
    wsf[F_WS + e] = sqrtf(__fmul_rn(spec, h2f));
  }
}

// v[o0, j]: o0 in [0,65), j in [0,129) (col offset j-64)
// grid (NCHUNK, 9): y = 16-column tile. acc[5] double2 per thread (no spill).
__launch_bounds__(256)
__global__ void k_v_main(const float* __restrict__ x, const float* __restrict__ wsf,
                         double* __restrict__ vpart){
  __shared__ float2 aL[16][80];
  __shared__ float2 bL[16][16];
  __shared__ float hxs[16][2];
  const float hf = wsf[F_H];
  const int tid = threadIdx.x;
  const int t0 = tid >> 4, t1 = tid & 15;
  const int jcol = blockIdx.y * 16 + t1;   // 0..143 (valid < 129)
  double2 acc[5];
  #pragma unroll
  for (int k = 0; k < 5; ++k) acc[k] = make_double2(0.0, 0.0);
  const int p0 = blockIdx.x * PTSB2;
  const int pend = min(p0 + PTSB2, NTRAIN);
  for (int base = p0; base < pend; base += 16){
    if (tid < 32){
      int p = tid >> 1, d = tid & 1;
      int gp = base + p;
      hxs[p][d] = (gp < pend) ? __fmul_rn(hf, x[2 * gp + d]) : 0.f;
    }
    __syncthreads();
    for (int i = tid; i < 16 * 80; i += 256){
      int p = i / 80;
      int o = i - p * 80;
      int gp = base + p;
      float2 va = make_float2(0.f, 0.f);
      if (gp < pend && o < 65){
        float t = __fmul_rn(hxs[p][0], (float)o);
        float sn, cs; sincosf(__fmul_rn(TPI32, t), &sn, &cs);
        va = make_float2(cs, -sn);
      }
      aL[p][o] = va;
    }
    {
      int p = t0, c = t1;
      int gp = base + p;
      int j = blockIdx.y * 16 + c;
      float2 vb = make_float2(0.f, 0.f);
      if (gp < pend && j < 129){
        float t = __fmul_rn(hxs[p][1], (float)(j - 64));
        float sn, cs; sincosf(__fmul_rn(TPI32, t), &sn, &cs);
        vb = make_float2(cs, -sn);
      }
      bL[p][c] = vb;
    }
    __syncthreads();
    #pragma unroll 1
    for (int p = 0; p < 16; ++p){
      float2 bv = bL[p][t1];
      float2 av[5];
      #pragma unroll
      for (int k = 0; k < 5; ++k) av[k] = aL[p][t0 + 16 * k];
      #pragma unroll
      for (int k = 0; k < 5; ++k){
        acc[k].x += (double)av[k].x * (double)bv.x - (double)av[k].y * (double)bv.y;
        acc[k].y += (double)av[k].x * (double)bv.y + (double)av[k].y * (double)bv.x;
      }
    }
    __syncthreads();
  }
  double* outp = vpart + (size_t)blockIdx.x * VH2;
  if (jcol < 129){
    #pragma unroll
    for (int k = 0; k < 5; ++k){
      int o0 = t0 + 16 * k;
      if (o0 < 65){
        int e = o0 * 129 + jcol;
        outp[2 * e] = acc[k].x;
        outp[2 * e + 1] = acc[k].y;
      }
    }
  }
}

// fk[o, c]: o in [0,33), c in [0,65) (freq c-32); grid (NCHUNK, 5)
__launch_bounds__(256)
__global__ void k_fk_main(const float* __restrict__ x, const float* __restrict__ y,
                          const float* __restrict__ wsf, double* __restrict__ fkpart){
  __shared__ float2 aL[16][48];
  __shared__ float2 bL[16][16];
  __shared__ float hxs[16][2];
  __shared__ float ys[16];
  const float hf = wsf[F_H];
  const int tid = threadIdx.x;
  const int t0 = tid >> 4, t1 = tid & 15;
  const int jcol = blockIdx.y * 16 + t1;   // 0..79 (valid < 65)
  double2 acc[3];
  #pragma unroll
  for (int k = 0; k < 3; ++k) acc[k] = make_double2(0.0, 0.0);
  const int p0 = blockIdx.x * PTSB2;
  const int pend = min(p0 + PTSB2, NTRAIN);
  for (int base = p0; base < pend; base += 16){
    if (tid < 32){
      int p = tid >> 1, d = tid & 1;
      int gp = base + p;
      hxs[p][d] = (gp < pend) ? __fmul_rn(hf, x[2 * gp + d]) : 0.f;
    } else if (tid < 48){
      int p = tid - 32;
      int gp = base + p;
      ys[p] = (gp < pend) ? y[gp] : 0.f;
    }
    __syncthreads();
    for (int i = tid; i < 16 * 48; i += 256){
      int p = i / 48, o = i - p * 48;
      int gp = base + p;
      float2 val = make_float2(0.f, 0.f);
      if (o < 33 && gp < pend){
        float t = __fmul_rn(hxs[p][0], (float)o);
        float sn, cs; sincosf(__fmul_rn(TPI32, t), &sn, &cs);
        val = make_float2(__fmul_rn(ys[p], cs), __fmul_rn(ys[p], -sn));
      }
      aL[p][o] = val;
    }
    {
      int p = t0, c = t1;
      int gp = base + p;
      int j = blockIdx.y * 16 + c;
      float2 vb = make_float2(0.f, 0.f);
      if (gp < pend && j < 65){
        float t = __fmul_rn(hxs[p][1], (float)(j - 32));
        float sn, cs; sincosf(__fmul_rn(TPI32, t), &sn, &cs);
        vb = make_float2(cs, -sn);
      }
      bL[p][c] = vb;
    }
    __syncthreads();
    #pragma unroll 1
    for (int p = 0; p < 16; ++p){
      float2 bv = bL[p][t1];
      float2 av[3];
      #pragma unroll
      for (int k = 0; k < 3; ++k) av[k] = aL[p][t0 + 16 * k];
      #pragma unroll
      for (int k = 0; k < 3; ++k){
        acc[k].x += (double)av[k].x * (double)bv.x - (double)av[k].y * (double)bv.y;
        acc[k].y += (double)av[k].x * (double)bv.y + (double)av[k].y * (double)bv.x;
      }
    }
    __syncthreads();
  }
  double* outp = fkpart + (size_t)blockIdx.x * FH2;
  if (jcol < 65){
    #pragma unroll
    for (int k = 0; k < 3; ++k){
      int o0 = t0 + 16 * k;
      if (o0 < 33){
        int e = o0 * 65 + jcol;
        outp[2 * e] = acc[k].x;
        outp[2 * e + 1] = acc[k].y;
      }
    }
  }
}

__global__ void k_reduce_v(const double* __restrict__ wsd, float* __restrict__ wsf){
  int e = blockIdx.x * blockDim.x + threadIdx.x;
  if (e >= VHALF) return;
  const double* vp = wsd + D_VPART;
  double sr = 0.0, si = 0.0;
  for (int k = 0; k < NCHUNK; ++k){
    sr += vp[(size_t)k * VH2 + 2 * e];
    si += vp[(size_t)k * VH2 + 2 * e + 1];
  }
  float r32 = (float)sr, i32 = (float)si;
  int o0 = e / 129, j = e - o0 * 129;
  float2* vF = (float2*)(wsf + F_VF);
  vF[(o0 + 64) * 129 + j] = make_float2(r32, i32);
  if (o0 > 0) vF[(64 - o0) * 129 + (128 - j)] = make_float2(r32, -i32);
}

__global__ void k_reduce_fk(const double* __restrict__ wsd, float* __restrict__ wsf){
  int e = blockIdx.x * blockDim.x + threadIdx.x;
  if (e >= FKHALF) return;
  const double* fp = wsd + D_FKPART;
  double sr = 0.0, si = 0.0;
  for (int k = 0; k < NCHUNK; ++k){
    sr += fp[(size_t)k * FH2 + 2 * e];
    si += fp[(size_t)k * FH2 + 2 * e + 1];
  }
  float fr = (float)sr, fi = (float)si;
  int a = e / 65, c = e - a * 65;
  int ef = (a + 32) * 65 + c;
  float wf = wsf[F_WS + ef];
  float* rhs = wsf + F_RHS;
  rhs[2 * ef] = __fmul_rn(wf, fr);
  rhs[2 * ef + 1] = __fmul_rn(wf, fi);
  if (a > 0){
    int ef2 = (32 - a) * 65 + (64 - c);
    float wf2 = wsf[F_WS + ef2];
    rhs[2 * ef2] = __fmul_rn(wf2, fr);
    rhs[2 * ef2 + 1] = -__fmul_rn(wf2, fi);
  }
}

// fused vhat: block p computes T1 row p (f64) then vhat row p (c64)
__launch_bounds__(192)
__global__ void k_vhat(float* __restrict__ wsf){
  __shared__ double twc[129], tws[129];
  __shared__ double t1r[129], t1i[129];
  int p = blockIdx.x, t = threadIdx.x;
  if (t < 129){
    double ang = TWO_PI_D * (double)t / 129.0;
    double s, c; sincos(ang, &s, &c);
    twc[t] = c; tws[t] = s;
  }
  __syncthreads();
  if (t < 129){
    const float2* vF = (const float2*)(wsf + F_VF);
    int n = t;
    int nsrc = (n + 64) % 129;
    double ar = 0.0, ai = 0.0;
    for (int m = 0; m < 129; ++m){
      float2 v = vF[((m + 64) % 129) * 129 + nsrc];
      int idx = (p * m) % 129;
      double wr = twc[idx], wi = -tws[idx];
      ar += (double)v.x * wr - (double)v.y * wi;
      ai += (double)v.x * wi + (double)v.y * wr;
    }
    t1r[n] = ar; t1i[n] = ai;
  }
  __syncthreads();
  if (t < 129){
    int q = t;
    double ar = 0.0, ai = 0.0;
    for (int n = 0; n < 129; ++n){
      int idx = (q * n) % 129;
      double wr = twc[idx], wi = -tws[idx];
      ar += t1r[n] * wr - t1i[n] * wi;
      ai += t1r[n] * wi + t1i[n] * wr;
    }
    ((float2*)(wsf + F_VHAT))[p * 129 + q] = make_float2((float)ar, (float)ai);
  }
}

__global__ void k_cg_init(float* __restrict__ wsf){
  int e = blockIdx.x * blockDim.x + threadIdx.x;
  if (e == 0){
    ((unsigned*)wsf)[F_CNT] = 0u;
    ((unsigned*)wsf)[F_GEN] = 0u;
  }
  if (e >= M2) return;
  const float2* rhs = (const float2*)(wsf + F_RHS);
  float2 b = rhs[e];
  ((float2*)(wsf + F_X))[e] = make_float2(0.f, 0.f);
  ((float2*)(wsf + F_R))[e] = b;
  ((float2*)(wsf + F_P))[e] = b;
  wsf[F_PB + e] = __fadd_rn(__fmul_rn(b.x, b.x), __fmul_rn(b.y, b.y));
}

// ---- numpy pairwise sum (exact replication), n = 4225 ----
__device__ __forceinline__ float pw_leaf(const float* d, int o, int n){
  float r0 = d[o], r1 = d[o+1], r2 = d[o+2], r3 = d[o+3];
  float r4 = d[o+4], r5 = d[o+5], r6 = d[o+6], r7 = d[o+7];
  int i = 8;
  int lim = n - (n & 7);
  for (; i < lim; i += 8){
    r0 = __fadd_rn(r0, d[o+i]);   r1 = __fadd_rn(r1, d[o+i+1]);
    r2 = __fadd_rn(r2, d[o+i+2]); r3 = __fadd_rn(r3, d[o+i+3]);
    r4 = __fadd_rn(r4, d[o+i+4]); r5 = __fadd_rn(r5, d[o+i+5]);
    r6 = __fadd_rn(r6, d[o+i+6]); r7 = __fadd_rn(r7, d[o+i+7]);
  }
  float res = __fadd_rn(__fadd_rn(__fadd_rn(r0, r1), __fadd_rn(r2, r3)),
                        __fadd_rn(__fadd_rn(r4, r5), __fadd_rn(r6, r7)));
  for (; i < n; ++i) res = __fadd_rn(res, d[o+i]);
  return res;
}

__device__ __forceinline__ void pw_tree(const float* pb, float* T, int tid){
  if (tid < 16){
    const int tb[16] = {0,264,528,792,1056,1320,1584,1848,
                        2112,2376,2640,2904,3168,3432,3696,3960};
    int base = tb[tid];
    int sz3 = (tid == 15) ? 73 : 72;
    float L0 = pw_leaf(pb, base, 128);
    float L1 = pw_leaf(pb, base + 128, 64);
    float L2 = pw_leaf(pb, base + 192, sz3);
    T[tid] = __fadd_rn(L0, __fadd_rn(L1, L2));
  }
  __syncthreads();
  if (tid == 0){
    float s0 = __fadd_rn(__fadd_rn(T[0], T[1]), __fadd_rn(T[2], T[3]));
    float s1 = __fadd_rn(__fadd_rn(T[4], T[5]), __fadd_rn(T[6], T[7]));
    float s2 = __fadd_rn(__fadd_rn(T[8], T[9]), __fadd_rn(T[10], T[11]));
    float s3 = __fadd_rn(__fadd_rn(T[12], T[13]), __fadd_rn(T[14], T[15]));
    T[0] = __fadd_rn(__fadd_rn(s0, s1), __fadd_rn(s2, s3));
  }
}

__launch_bounds__(256)
__global__ void k_pair0(float* __restrict__ wsf){
  __shared__ float pb[M2];
  __shared__ float T[16];
  int tid = threadIdx.x;
  for (int i = tid; i < M2; i += 256) pb[i] = wsf[F_PB + i];
  __syncthreads();
  pw_tree(pb, T, tid);
  __syncthreads();
  if (tid == 0) wsf[F_RS] = T[0];
}

// software grid barrier: all 129 blocks co-resident (129 <= 256 CUs).
// __syncthreads drains block stores (vmcnt0); release fence -> arrive -> spin
// on generation; acquire fence -> proceed. Generation scheme is ABA-safe.
__device__ __forceinline__ void gridbar(unsigned* cnt, unsigned* gen){
  __syncthreads();
  if (threadIdx.x == 0){
    __threadfence();                       // release (device scope)
    unsigned g = atomicAdd(gen, 0u);
    unsigned old = atomicAdd(cnt, 1u);
    if (old == NBLK - 1u){
      atomicExch(cnt, 0u);
      __threadfence();
      atomicAdd(gen, 1u);
    } else {
      while (atomicAdd(gen, 0u) == g){ __builtin_amdgcn_s_sleep(4); }
    }
    __threadfence();                       // acquire (device scope)
  }
  __syncthreads();
}

// ---- the entire 30-iteration CG loop as ONE plain kernel (129 blocks) ----
// Phase A (wfft+vhat-mul): all 129 blocks. Phase B (ifft+Ap+pb): blocks 0..64.
// Phase C (scalars+updates): block 0. Arithmetic verbatim from R13 kernels.
__launch_bounds__(256)
__global__ void k_cgloop(float* __restrict__ wsf){
  __shared__ double twc[129], tws[129];
  __shared__ double d1[129], d2[129];
  __shared__ float pb[M2];
  __shared__ float T[16];
  __shared__ float sh[2];
  const int bid = blockIdx.x;
  const int t = threadIdx.x;
  unsigned* cnt = ((unsigned*)wsf) + F_CNT;
  unsigned* gen = ((unsigned*)wsf) + F_GEN;
  if (t < 129){
    double ang = TWO_PI_D * (double)t / 129.0;
    double s, c; sincos(ang, &s, &c);
    twc[t] = c; tws[t] = s;
  }
  __syncthreads();
  float2* PROD = (float2*)(wsf + F_PROD);
  const float2* VHAT = (const float2*)(wsf + F_VHAT);
  float2* X = (float2*)(wsf + F_X);
  float2* R = (float2*)(wsf + F_R);
  float2* P = (float2*)(wsf + F_P);
  float2* AP = (float2*)(wsf + F_AP);
  const float* W = wsf + F_WS;

  for (int it = 0; it < CGITERS; ++it){
    // ---- Phase A: block pr=bid computes PROD row pr ----
    {
      const int pr = bid;
      if (t < 65){
        int n = t;
        double ar = 0.0, ai = 0.0;
        int idx = 0;
        for (int m = 0; m < 65; ++m){
          int e = m * 65 + n;
          float2 p = P[e];
          float w = W[e];
          float wbr = __fmul_rn(w, p.x), wbi = __fmul_rn(w, p.y);
          double wr = twc[idx], wi = -tws[idx];
          ar += (double)wbr * wr - (double)wbi * wi;
          ai += (double)wbr * wi + (double)wbi * wr;
          idx += pr; if (idx >= 129) idx -= 129;
        }
        d1[n] = ar; d2[n] = ai;
      }
      __syncthreads();
      if (t < 129){
        int q = t;
        double ar = 0.0, ai = 0.0;
        int idx = 0;
        for (int n = 0; n < 65; ++n){
          double wr = twc[idx], wi = -tws[idx];
          ar += d1[n] * wr - d2[n] * wi;
          ai += d1[n] * wi + d2[n] * wr;
          idx += q; if (idx >= 129) idx -= 129;
        }
        float Wr = (float)ar, Wi = (float)ai;   // c64 cast of fftn output
        float2 v = VHAT[pr * 129 + q];
        float prre = __fsub_rn(__fmul_rn(v.x, Wr), __fmul_rn(v.y, Wi));
        float prim = __fadd_rn(__fmul_rn(v.x, Wi), __fmul_rn(v.y, Wr));
        PROD[pr * 129 + q] = make_float2(prre, prim);
      }
    }
    gridbar(cnt, gen);
    // ---- Phase B: blocks m=bid<65 compute Ap row m ----
    if (bid < 65){
      const int m = bid;
      if (t < 129){
        int q = t;
        double ar = 0.0, ai = 0.0;
        int idx = 0;
        for (int pr = 0; pr < 129; ++pr){
          float2 v = PROD[pr * 129 + q];
          double wr = twc[idx], wi = tws[idx];   // e^{+i}
          ar += (double)v.x * wr - (double)v.y * wi;
          ai += (double)v.x * wi + (double)v.y * wr;
          idx += m; if (idx >= 129) idx -= 129;
        }
        const double sc = 1.0 / 129.0;
        d1[q] = ar * sc; d2[q] = ai * sc;
      }
      __syncthreads();
      if (t < 65){
        int n = t;
        double ar = 0.0, ai = 0.0;
        int idx = 0;
        for (int q = 0; q < 129; ++q){
          double wr = twc[idx], wi = tws[idx];   // e^{+i}
          ar += d1[q] * wr - d2[q] * wi;
          ai += d1[q] * wi + d2[q] * wr;
          idx += n; if (idx >= 129) idx -= 129;
        }
        const double sc = 1.0 / 129.0;
        float Twr = (float)(ar * sc), Twi = (float)(ai * sc);  // c64 cast
        int e = m * 65 + n;
        float w = W[e];
        float2 p = P[e];
        float Apx = __fadd_rn(__fmul_rn(w, Twr), __fmul_rn(0.05f, p.x));
        float Apy = __fadd_rn(__fmul_rn(w, Twi), __fmul_rn(0.05f, p.y));
        AP[e] = make_float2(Apx, Apy);
        wsf[F_PB + e] = __fadd_rn(__fmul_rn(p.x, Apx), __fmul_rn(p.y, Apy));
      }
    }
    gridbar(cnt, gen);
    // ---- Phase C: block 0 scalar step + vector updates ----
    if (bid == 0){
      for (int i = t; i < M2; i += 256) pb[i] = wsf[F_PB + i];
      __syncthreads();
      pw_tree(pb, T, t);      // pAp
      __syncthreads();
      if (t == 0){
        float rs = wsf[F_RS];
        sh[1] = rs;
        sh[0] = __fdiv_rn(rs, T[0]);   // alpha
      }
      __syncthreads();
      float alpha = sh[0];
      for (int e = t; e < M2; e += 256){
        float2 p = P[e], ap = AP[e], xv = X[e], rv = R[e];
        xv.x = __fadd_rn(xv.x, __fmul_rn(alpha, p.x));
        xv.y = __fadd_rn(xv.y, __fmul_rn(alpha, p.y));
        rv.x = __fsub_rn(rv.x, __fmul_rn(alpha, ap.x));
        rv.y = __fsub_rn(rv.y, __fmul_rn(alpha, ap.y));
        X[e] = xv; R[e] = rv;
        pb[e] = __fadd_rn(__fmul_rn(rv.x, rv.x), __fmul_rn(rv.y, rv.y));
      }
      __syncthreads();
      pw_tree(pb, T, t);      // rsn
      __syncthreads();
      if (t == 0){
        float rsn = T[0];
        sh[0] = __fdiv_rn(rsn, sh[1]);  // beta
        wsf[F_RS] = rsn;
      }
      __syncthreads();
      float beta = sh[0];
      for (int e = t; e < M2; e += 256){
        float2 rv = R[e], p = P[e];
        P[e] = make_float2(__fadd_rn(rv.x, __fmul_rn(beta, p.x)),
                           __fadd_rn(rv.y, __fmul_rn(beta, p.y)));
      }
    }
    gridbar(cnt, gen);
  }
}

__launch_bounds__(256)
__global__ void k_predict(const float* __restrict__ xn, const float* __restrict__ wsf,
                          float* __restrict__ out){
  __shared__ double fbRe[M2];
  __shared__ double fbIm[M2];
  const float hf = wsf[F_H];
  const float* wsq = wsf + F_WS;
  const float2* xb = (const float2*)(wsf + F_X);
  int tid = threadIdx.x;
  for (int i = tid; i < M2; i += 256){
    float w = wsq[i]; float2 q = xb[i];
    fbRe[i] = (double)__fmul_rn(w, q.x);
    fbIm[i] = (double)__fmul_rn(w, q.y);
  }
  __syncthreads();
  int lane = tid & 63;
  int wid = (blockIdx.x * 256 + tid) >> 6;
  int nw = (gridDim.x * 256) >> 6;
  for (int n = wid; n < NTEST; n += nw){
    float hx0 = __fmul_rn(hf, xn[2 * n]);
    float hx1 = __fmul_rn(hf, xn[2 * n + 1]);
    float t0 = __fmul_rn(hx0, (float)(lane - 32));
    float s0, c0; sincosf(__fmul_rn(TPI32, t0), &s0, &c0);
    float t1 = __fmul_rn(hx1, (float)(lane - 32));
    float s1, c1; sincosf(__fmul_rn(TPI32, t1), &s1, &c1);
    float t0x = __fmul_rn(hx0, 32.0f);
    float s0x, c0x; sincosf(__fmul_rn(TPI32, t0x), &s0x, &c0x);
    float t1x = __fmul_rn(hx1, 32.0f);
    float s1x, c1x; sincosf(__fmul_rn(TPI32, t1x), &s1x, &c1x);
    double e0r = (double)c0, e0i = (double)s0;
    double e1r = (double)c1, e1i = (double)s1;
    double gr = 0.0, gi = 0.0;
    for (int a = 0; a < 64; ++a){
      double er = __shfl(e0r, a, 64);
      double ei = __shfl(e0i, a, 64);
      double fr = fbRe[a * 65 + lane];
      double fi = fbIm[a * 65 + lane];
      gr += fr * er - fi * ei;
      gi += fr * ei + fi * er;
    }
    {
      double fr = fbRe[64 * 65 + lane], fi = fbIm[64 * 65 + lane];
      gr += fr * (double)c0x - fi * (double)s0x;
      gi += fr * (double)s0x + fi * (double)c0x;
    }
    double contrib = gr * e1r - gi * e1i;
    {
      double fr = fbRe[lane * 65 + 64], fi = fbIm[lane * 65 + 64];
      double ur = fr * e0r - fi * e0i;
      double ui = fr * e0i + fi * e0r;
      contrib += ur * (double)c1x - ui * (double)s1x;
      if (lane == 0){
        double fr2 = fbRe[64 * 65 + 64], fi2 = fbIm[64 * 65 + 64];
        double vr = fr2 * (double)c0x - fi2 * (double)s0x;
        double vi = fr2 * (double)s0x + fi2 * (double)c0x;
        contrib += vr * (double)c1x - vi * (double)s1x;
      }
    }
    for (int off = 32; off; off >>= 1) contrib += __shfl_xor(contrib, off, 64);
    if (lane == 0) out[n] = (float)contrib;
  }
}

extern "C" void kernel_launch(void* const* d_in, const int* in_sizes, int n_in,
                              void* d_out, int out_size, void* d_ws, size_t ws_size,
                              hipStream_t stream){
  const float* x = (const float*)d_in[0];
  const float* y = (const float*)d_in[1];
  const float* xnew = (const float*)d_in[2];
  float* wsf = (float*)d_ws;
  double* wsd = (double*)d_ws;
  float* out = (float*)d_out;
  unsigned* mm = (unsigned*)(wsf + 4);

  k_init<<<1, 64, 0, stream>>>(mm);
  k_minmax<<<256, 256, 0, stream>>>(x, xnew, mm);
  k_setup<<<1, 256, 0, stream>>>(wsf);
  k_v_main<<<dim3(NCHUNK, 9), 256, 0, stream>>>(x, wsf, wsd + D_VPART);
  k_fk_main<<<dim3(NCHUNK, 5), 256, 0, stream>>>(x, y, wsf, wsd + D_FKPART);
  k_reduce_v<<<33, 256, 0, stream>>>(wsd, wsf);
  k_reduce_fk<<<9, 256, 0, stream>>>(wsd, wsf);
  k_vhat<<<129, 192, 0, stream>>>(wsf);
  k_cg_init<<<17, 256, 0, stream>>>(wsf);
  k_pair0<<<1, 256, 0, stream>>>(wsf);
  k_cgloop<<<129, 256, 0, stream>>>(wsf);
  k_predict<<<256, 256, 0, stream>>>(xnew, wsf, out);
}

// Round 16
// 3080.888 us; speedup vs baseline: 1.0136x; 1.0136x over previous
//
#include <hip/hip_runtime.h>
#include <math.h>

#define M2 4225
#define NTRAIN 100000
#define NTEST 50000
#define CGITERS 30
#define TWO_PI_D 6.283185307179586476925287
#define TPI32 6.28318530717958647692f

// ---- float offsets ----
#define F_H 0
#define F_RS 1
#define F_CNT 2         // software-barrier counter (unsigned)
#define F_GEN 3         // software-barrier generation (unsigned)
// mm encoded uints at floats 4..7
#define F_WS 8          // 4225
#define F_RHS 4234      // 8450 (float2)
#define F_X 12684
#define F_R 21134
#define F_P 29584
#define F_AP 38034
#define F_PB 46484      // 4225 products
#define F_VF 50710      // 129*129 float2 = 33282
#define F_VHAT 83992    // 33282
#define F_PROD 117274   // 33282 (end 150556)
// ---- double offsets ----
#define D_VPART 125330  // 128*16770
#define D_FKPART 2271890 // 128*4290 (end 2821010 dbl = 22.6MB)

#define NCHUNK 128
#define PTSB2 782
#define VHALF 8385
#define VH2 16770
#define FKHALF 2145
#define FH2 4290
#define NBLK 129u

__device__ __forceinline__ unsigned fkey(float f){
  unsigned u = __float_as_uint(f);
  return (u & 0x80000000u) ? ~u : (u | 0x80000000u);
}
__device__ __forceinline__ float fdec(unsigned k){
  unsigned u = (k & 0x80000000u) ? (k & 0x7fffffffu) : ~k;
  return __uint_as_float(u);
}

__global__ void k_init(unsigned* mm){
  if (threadIdx.x == 0){
    mm[0] = 0xFFFFFFFFu; mm[1] = 0u; mm[2] = 0xFFFFFFFFu; mm[3] = 0u;
  }
}

__global__ void k_minmax(const float* __restrict__ x, const float* __restrict__ xn,
                         unsigned* __restrict__ mm){
  int tid = blockIdx.x * blockDim.x + threadIdx.x;
  int str = gridDim.x * blockDim.x;
  float mn0 = 1e30f, mx0 = -1e30f, mn1 = 1e30f, mx1 = -1e30f;
  const float2* a = (const float2*)x;
  for (int i = tid; i < NTRAIN; i += str){
    float2 v = a[i];
    mn0 = fminf(mn0, v.x); mx0 = fmaxf(mx0, v.x);
    mn1 = fminf(mn1, v.y); mx1 = fmaxf(mx1, v.y);
  }
  const float2* b = (const float2*)xn;
  for (int i = tid; i < NTEST; i += str){
    float2 v = b[i];
    mn0 = fminf(mn0, v.x); mx0 = fmaxf(mx0, v.x);
    mn1 = fminf(mn1, v.y); mx1 = fmaxf(mx1, v.y);
  }
  for (int off = 32; off; off >>= 1){
    mn0 = fminf(mn0, __shfl_xor(mn0, off, 64));
    mx0 = fmaxf(mx0, __shfl_xor(mx0, off, 64));
    mn1 = fminf(mn1, __shfl_xor(mn1, off, 64));
    mx1 = fmaxf(mx1, __shfl_xor(mx1, off, 64));
  }
  if ((threadIdx.x & 63) == 0){
    atomicMin(&mm[0], fkey(mn0)); atomicMax(&mm[1], fkey(mx0));
    atomicMin(&mm[2], fkey(mn1)); atomicMax(&mm[3], fkey(mx1));
  }
}

__global__ void k_setup(float* __restrict__ wsf){
  const unsigned* mm = (const unsigned*)(wsf + 4);
  float mn0 = fdec(mm[0]), mx0 = fdec(mm[1]);
  float mn1 = fdec(mm[2]), mx1 = fdec(mm[3]);
  float d0 = __fsub_rn(mx0, mn0), d1 = __fsub_rn(mx1, mn1);
  float L = fmaxf(d0, d1);
  if (L <= 1e-9f) L = 1.0f;
  float hf = __fdiv_rn(1.0f, L);
  if (threadIdx.x == 0) wsf[F_H] = hf;
  const float c0f = (float)(TWO_PI_D * 0.01);
  const float c1f = (float)(-2.0 * 9.869604401089358618834 * 0.01);
  float h2f = __fmul_rn(hf, hf);
  for (int e = threadIdx.x; e < M2; e += blockDim.x){
    int r = e / 65, c = e - r * 65;
    float xi0 = __fmul_rn(hf, (float)(r - 32));
    float xi1 = __fmul_rn(hf, (float)(c - 32));
    float sq = __fadd_rn(__fmul_rn(xi0, xi0), __fmul_rn(xi1, xi1));
    float spec = __fmul_rn(c0f, expf(__fmul_rn(c1f, sq)));
    wsf[F_WS + e] = sqrtf(__fmul_rn(spec, h2f));
  }
}

// v[o0, j]: o0 in [0,65), j in [0,129) (col offset j-64)
// grid (NCHUNK, 9): y = 16-column tile. acc[5] double2 per thread (no spill).
__launch_bounds__(256)
__global__ void k_v_main(const float* __restrict__ x, const float* __restrict__ wsf,
                         double* __restrict__ vpart){
  __shared__ float2 aL[16][80];
  __shared__ float2 bL[16][16];
  __shared__ float hxs[16][2];
  const float hf = wsf[F_H];
  const int tid = threadIdx.x;
  const int t0 = tid >> 4, t1 = tid & 15;
  const int jcol = blockIdx.y * 16 + t1;   // 0..143 (valid < 129)
  double2 acc[5];
  #pragma unroll
  for (int k = 0; k < 5; ++k) acc[k] = make_double2(0.0, 0.0);
  const int p0 = blockIdx.x * PTSB2;
  const int pend = min(p0 + PTSB2, NTRAIN);
  for (int base = p0; base < pend; base += 16){
    if (tid < 32){
      int p = tid >> 1, d = tid & 1;
      int gp = base + p;
      hxs[p][d] = (gp < pend) ? __fmul_rn(hf, x[2 * gp + d]) : 0.f;
    }
    __syncthreads();
    for (int i = tid; i < 16 * 80; i += 256){
      int p = i / 80;
      int o = i - p * 80;
      int gp = base + p;
      float2 va = make_float2(0.f, 0.f);
      if (gp < pend && o < 65){
        float t = __fmul_rn(hxs[p][0], (float)o);
        float sn, cs; sincosf(__fmul_rn(TPI32, t), &sn, &cs);
        va = make_float2(cs, -sn);
      }
      aL[p][o] = va;
    }
    {
      int p = t0, c = t1;
      int gp = base + p;
      int j = blockIdx.y * 16 + c;
      float2 vb = make_float2(0.f, 0.f);
      if (gp < pend && j < 129){
        float t = __fmul_rn(hxs[p][1], (float)(j - 64));
        float sn, cs; sincosf(__fmul_rn(TPI32, t), &sn, &cs);
        vb = make_float2(cs, -sn);
      }
      bL[p][c] = vb;
    }
    __syncthreads();
    #pragma unroll 1
    for (int p = 0; p < 16; ++p){
      float2 bv = bL[p][t1];
      float2 av[5];
      #pragma unroll
      for (int k = 0; k < 5; ++k) av[k] = aL[p][t0 + 16 * k];
      #pragma unroll
      for (int k = 0; k < 5; ++k){
        acc[k].x += (double)av[k].x * (double)bv.x - (double)av[k].y * (double)bv.y;
        acc[k].y += (double)av[k].x * (double)bv.y + (double)av[k].y * (double)bv.x;
      }
    }
    __syncthreads();
  }
  double* outp = vpart + (size_t)blockIdx.x * VH2;
  if (jcol < 129){
    #pragma unroll
    for (int k = 0; k < 5; ++k){
      int o0 = t0 + 16 * k;
      if (o0 < 65){
        int e = o0 * 129 + jcol;
        outp[2 * e] = acc[k].x;
        outp[2 * e + 1] = acc[k].y;
      }
    }
  }
}

// fk[o, c]: o in [0,33), c in [0,65) (freq c-32); grid (NCHUNK, 5)
__launch_bounds__(256)
__global__ void k_fk_main(const float* __restrict__ x, const float* __restrict__ y,
                          const float* __restrict__ wsf, double* __restrict__ fkpart){
  __shared__ float2 aL[16][48];
  __shared__ float2 bL[16][16];
  __shared__ float hxs[16][2];
  __shared__ float ys[16];
  const float hf = wsf[F_H];
  const int tid = threadIdx.x;
  const int t0 = tid >> 4, t1 = tid & 15;
  const int jcol = blockIdx.y * 16 + t1;   // 0..79 (valid < 65)
  double2 acc[3];
  #pragma unroll
  for (int k = 0; k < 3; ++k) acc[k] = make_double2(0.0, 0.0);
  const int p0 = blockIdx.x * PTSB2;
  const int pend = min(p0 + PTSB2, NTRAIN);
  for (int base = p0; base < pend; base += 16){
    if (tid < 32){
      int p = tid >> 1, d = tid & 1;
      int gp = base + p;
      hxs[p][d] = (gp < pend) ? __fmul_rn(hf, x[2 * gp + d]) : 0.f;
    } else if (tid < 48){
      int p = tid - 32;
      int gp = base + p;
      ys[p] = (gp < pend) ? y[gp] : 0.f;
    }
    __syncthreads();
    for (int i = tid; i < 16 * 48; i += 256){
      int p = i / 48, o = i - p * 48;
      int gp = base + p;
      float2 val = make_float2(0.f, 0.f);
      if (o < 33 && gp < pend){
        float t = __fmul_rn(hxs[p][0], (float)o);
        float sn, cs; sincosf(__fmul_rn(TPI32, t), &sn, &cs);
        val = make_float2(__fmul_rn(ys[p], cs), __fmul_rn(ys[p], -sn));
      }
      aL[p][o] = val;
    }
    {
      int p = t0, c = t1;
      int gp = base + p;
      int j = blockIdx.y * 16 + c;
      float2 vb = make_float2(0.f, 0.f);
      if (gp < pend && j < 65){
        float t = __fmul_rn(hxs[p][1], (float)(j - 32));
        float sn, cs; sincosf(__fmul_rn(TPI32, t), &sn, &cs);
        vb = make_float2(cs, -sn);
      }
      bL[p][c] = vb;
    }
    __syncthreads();
    #pragma unroll 1
    for (int p = 0; p < 16; ++p){
      float2 bv = bL[p][t1];
      float2 av[3];
      #pragma unroll
      for (int k = 0; k < 3; ++k) av[k] = aL[p][t0 + 16 * k];
      #pragma unroll
      for (int k = 0; k < 3; ++k){
        acc[k].x += (double)av[k].x * (double)bv.x - (double)av[k].y * (double)bv.y;
        acc[k].y += (double)av[k].x * (double)bv.y + (double)av[k].y * (double)bv.x;
      }
    }
    __syncthreads();
  }
  double* outp = fkpart + (size_t)blockIdx.x * FH2;
  if (jcol < 65){
    #pragma unroll
    for (int k = 0; k < 3; ++k){
      int o0 = t0 + 16 * k;
      if (o0 < 33){
        int e = o0 * 65 + jcol;
        outp[2 * e] = acc[k].x;
        outp[2 * e + 1] = acc[k].y;
      }
    }
  }
}

__global__ void k_reduce_v(const double* __restrict__ wsd, float* __restrict__ wsf){
  int e = blockIdx.x * blockDim.x + threadIdx.x;
  if (e >= VHALF) return;
  const double* vp = wsd + D_VPART;
  double sr = 0.0, si = 0.0;
  for (int k = 0; k < NCHUNK; ++k){
    sr += vp[(size_t)k * VH2 + 2 * e];
    si += vp[(size_t)k * VH2 + 2 * e + 1];
  }
  float r32 = (float)sr, i32 = (float)si;
  int o0 = e / 129, j = e - o0 * 129;
  float2* vF = (float2*)(wsf + F_VF);
  vF[(o0 + 64) * 129 + j] = make_float2(r32, i32);
  if (o0 > 0) vF[(64 - o0) * 129 + (128 - j)] = make_float2(r32, -i32);
}

__global__ void k_reduce_fk(const double* __restrict__ wsd, float* __restrict__ wsf){
  int e = blockIdx.x * blockDim.x + threadIdx.x;
  if (e >= FKHALF) return;
  const double* fp = wsd + D_FKPART;
  double sr = 0.0, si = 0.0;
  for (int k = 0; k < NCHUNK; ++k){
    sr += fp[(size_t)k * FH2 + 2 * e];
    si += fp[(size_t)k * FH2 + 2 * e + 1];
  }
  float fr = (float)sr, fi = (float)si;
  int a = e / 65, c = e - a * 65;
  int ef = (a + 32) * 65 + c;
  float wf = wsf[F_WS + ef];
  float* rhs = wsf + F_RHS;
  rhs[2 * ef] = __fmul_rn(wf, fr);
  rhs[2 * ef + 1] = __fmul_rn(wf, fi);
  if (a > 0){
    int ef2 = (32 - a) * 65 + (64 - c);
    float wf2 = wsf[F_WS + ef2];
    rhs[2 * ef2] = __fmul_rn(wf2, fr);
    rhs[2 * ef2 + 1] = -__fmul_rn(wf2, fi);
  }
}

// fused vhat: block p computes T1 row p (f64) then vhat row p (c64)
__launch_bounds__(192)
__global__ void k_vhat(float* __restrict__ wsf){
  __shared__ double twc[129], tws[129];
  __shared__ double t1r[129], t1i[129];
  int p = blockIdx.x, t = threadIdx.x;
  if (t < 129){
    double ang = TWO_PI_D * (double)t / 129.0;
    double s, c; sincos(ang, &s, &c);
    twc[t] = c; tws[t] = s;
  }
  __syncthreads();
  if (t < 129){
    const float2* vF = (const float2*)(wsf + F_VF);
    int n = t;
    int nsrc = (n + 64) % 129;
    double ar = 0.0, ai = 0.0;
    for (int m = 0; m < 129; ++m){
      float2 v = vF[((m + 64) % 129) * 129 + nsrc];
      int idx = (p * m) % 129;
      double wr = twc[idx], wi = -tws[idx];
      ar += (double)v.x * wr - (double)v.y * wi;
      ai += (double)v.x * wi + (double)v.y * wr;
    }
    t1r[n] = ar; t1i[n] = ai;
  }
  __syncthreads();
  if (t < 129){
    int q = t;
    double ar = 0.0, ai = 0.0;
    for (int n = 0; n < 129; ++n){
      int idx = (q * n) % 129;
      double wr = twc[idx], wi = -tws[idx];
      ar += t1r[n] * wr - t1i[n] * wi;
      ai += t1r[n] * wi + t1i[n] * wr;
    }
    ((float2*)(wsf + F_VHAT))[p * 129 + q] = make_float2((float)ar, (float)ai);
  }
}

__global__ void k_cg_init(float* __restrict__ wsf){
  int e = blockIdx.x * blockDim.x + threadIdx.x;
  if (e == 0){
    ((unsigned*)wsf)[F_CNT] = 0u;
    ((unsigned*)wsf)[F_GEN] = 0u;
  }
  if (e >= M2) return;
  const float2* rhs = (const float2*)(wsf + F_RHS);
  float2 b = rhs[e];
  ((float2*)(wsf + F_X))[e] = make_float2(0.f, 0.f);
  ((float2*)(wsf + F_R))[e] = b;
  ((float2*)(wsf + F_P))[e] = b;
  wsf[F_PB + e] = __fadd_rn(__fmul_rn(b.x, b.x), __fmul_rn(b.y, b.y));
}

// ---- numpy pairwise sum (exact replication), n = 4225 ----
__device__ __forceinline__ float pw_leaf(const float* d, int o, int n){
  float r0 = d[o], r1 = d[o+1], r2 = d[o+2], r3 = d[o+3];
  float r4 = d[o+4], r5 = d[o+5], r6 = d[o+6], r7 = d[o+7];
  int i = 8;
  int lim = n - (n & 7);
  for (; i < lim; i += 8){
    r0 = __fadd_rn(r0, d[o+i]);   r1 = __fadd_rn(r1, d[o+i+1]);
    r2 = __fadd_rn(r2, d[o+i+2]); r3 = __fadd_rn(r3, d[o+i+3]);
    r4 = __fadd_rn(r4, d[o+i+4]); r5 = __fadd_rn(r5, d[o+i+5]);
    r6 = __fadd_rn(r6, d[o+i+6]); r7 = __fadd_rn(r7, d[o+i+7]);
  }
  float res = __fadd_rn(__fadd_rn(__fadd_rn(r0, r1), __fadd_rn(r2, r3)),
                        __fadd_rn(__fadd_rn(r4, r5), __fadd_rn(r6, r7)));
  for (; i < n; ++i) res = __fadd_rn(res, d[o+i]);
  return res;
}

__device__ __forceinline__ void pw_tree(const float* pb, float* T, int tid){
  if (tid < 16){
    const int tb[16] = {0,264,528,792,1056,1320,1584,1848,
                        2112,2376,2640,2904,3168,3432,3696,3960};
    int base = tb[tid];
    int sz3 = (tid == 15) ? 73 : 72;
    float L0 = pw_leaf(pb, base, 128);
    float L1 = pw_leaf(pb, base + 128, 64);
    float L2 = pw_leaf(pb, base + 192, sz3);
    T[tid] = __fadd_rn(L0, __fadd_rn(L1, L2));
  }
  __syncthreads();
  if (tid == 0){
    float s0 = __fadd_rn(__fadd_rn(T[0], T[1]), __fadd_rn(T[2], T[3]));
    float s1 = __fadd_rn(__fadd_rn(T[4], T[5]), __fadd_rn(T[6], T[7]));
    float s2 = __fadd_rn(__fadd_rn(T[8], T[9]), __fadd_rn(T[10], T[11]));
    float s3 = __fadd_rn(__fadd_rn(T[12], T[13]), __fadd_rn(T[14], T[15]));
    T[0] = __fadd_rn(__fadd_rn(s0, s1), __fadd_rn(s2, s3));
  }
}

__launch_bounds__(256)
__global__ void k_pair0(float* __restrict__ wsf){
  __shared__ float pb[M2];
  __shared__ float T[16];
  int tid = threadIdx.x;
  for (int i = tid; i < M2; i += 256) pb[i] = wsf[F_PB + i];
  __syncthreads();
  pw_tree(pb, T, tid);
  __syncthreads();
  if (tid == 0) wsf[F_RS] = T[0];
}

// software grid barrier: all 129 blocks co-resident (129 <= 256 CUs).
// Arrive: one fetch_add per block. Spin: plain agent-scope atomic LOADS
// (no RMW -> no atomic-unit serialization; R15's RMW-poll cost ~19us/barrier).
__device__ __forceinline__ void gridbar(unsigned* cnt, unsigned* gen){
  __syncthreads();
  if (threadIdx.x == 0){
    __threadfence();                       // release (device scope)
    unsigned g = __hip_atomic_load(gen, __ATOMIC_RELAXED, __HIP_MEMORY_SCOPE_AGENT);
    unsigned old = __hip_atomic_fetch_add(cnt, 1u, __ATOMIC_ACQ_REL, __HIP_MEMORY_SCOPE_AGENT);
    if (old == NBLK - 1u){
      __hip_atomic_store(cnt, 0u, __ATOMIC_RELAXED, __HIP_MEMORY_SCOPE_AGENT);
      __hip_atomic_fetch_add(gen, 1u, __ATOMIC_RELEASE, __HIP_MEMORY_SCOPE_AGENT);
    } else {
      while (__hip_atomic_load(gen, __ATOMIC_RELAXED, __HIP_MEMORY_SCOPE_AGENT) == g){
        __builtin_amdgcn_s_sleep(8);
      }
    }
    __threadfence();                       // acquire (device scope)
  }
  __syncthreads();
}

// ---- the entire 30-iteration CG loop as ONE plain kernel (129 blocks) ----
// Phase A (wfft+vhat-mul): all 129 blocks. Phase B (ifft+Ap+pb): blocks 0..64.
// Phase C (scalars+updates): block 0. Arithmetic verbatim from R13 kernels.
__launch_bounds__(256)
__global__ void k_cgloop(float* __restrict__ wsf){
  __shared__ double twc[129], tws[129];
  __shared__ double d1[129], d2[129];
  __shared__ float pb[M2];
  __shared__ float T[16];
  __shared__ float sh[2];
  const int bid = blockIdx.x;
  const int t = threadIdx.x;
  unsigned* cnt = ((unsigned*)wsf) + F_CNT;
  unsigned* gen = ((unsigned*)wsf) + F_GEN;
  if (t < 129){
    double ang = TWO_PI_D * (double)t / 129.0;
    double s, c; sincos(ang, &s, &c);
    twc[t] = c; tws[t] = s;
  }
  __syncthreads();
  float2* PROD = (float2*)(wsf + F_PROD);
  const float2* VHAT = (const float2*)(wsf + F_VHAT);
  float2* X = (float2*)(wsf + F_X);
  float2* R = (float2*)(wsf + F_R);
  float2* P = (float2*)(wsf + F_P);
  float2* AP = (float2*)(wsf + F_AP);
  const float* W = wsf + F_WS;

  for (int it = 0; it < CGITERS; ++it){
    // ---- Phase A: block pr=bid computes PROD row pr ----
    {
      const int pr = bid;
      if (t < 65){
        int n = t;
        double ar = 0.0, ai = 0.0;
        int idx = 0;
        for (int m = 0; m < 65; ++m){
          int e = m * 65 + n;
          float2 p = P[e];
          float w = W[e];
          float wbr = __fmul_rn(w, p.x), wbi = __fmul_rn(w, p.y);
          double wr = twc[idx], wi = -tws[idx];
          ar += (double)wbr * wr - (double)wbi * wi;
          ai += (double)wbr * wi + (double)wbi * wr;
          idx += pr; if (idx >= 129) idx -= 129;
        }
        d1[n] = ar; d2[n] = ai;
      }
      __syncthreads();
      if (t < 129){
        int q = t;
        double ar = 0.0, ai = 0.0;
        int idx = 0;
        for (int n = 0; n < 65; ++n){
          double wr = twc[idx], wi = -tws[idx];
          ar += d1[n] * wr - d2[n] * wi;
          ai += d1[n] * wi + d2[n] * wr;
          idx += q; if (idx >= 129) idx -= 129;
        }
        float Wr = (float)ar, Wi = (float)ai;   // c64 cast of fftn output
        float2 v = VHAT[pr * 129 + q];
        float prre = __fsub_rn(__fmul_rn(v.x, Wr), __fmul_rn(v.y, Wi));
        float prim = __fadd_rn(__fmul_rn(v.x, Wi), __fmul_rn(v.y, Wr));
        PROD[pr * 129 + q] = make_float2(prre, prim);
      }
    }
    gridbar(cnt, gen);
    // ---- Phase B: blocks m=bid<65 compute Ap row m ----
    if (bid < 65){
      const int m = bid;
      if (t < 129){
        int q = t;
        double ar = 0.0, ai = 0.0;
        int idx = 0;
        for (int pr = 0; pr < 129; ++pr){
          float2 v = PROD[pr * 129 + q];
          double wr = twc[idx], wi = tws[idx];   // e^{+i}
          ar += (double)v.x * wr - (double)v.y * wi;
          ai += (double)v.x * wi + (double)v.y * wr;
          idx += m; if (idx >= 129) idx -= 129;
        }
        const double sc = 1.0 / 129.0;
        d1[q] = ar * sc; d2[q] = ai * sc;
      }
      __syncthreads();
      if (t < 65){
        int n = t;
        double ar = 0.0, ai = 0.0;
        int idx = 0;
        for (int q = 0; q < 129; ++q){
          double wr = twc[idx], wi = tws[idx];   // e^{+i}
          ar += d1[q] * wr - d2[q] * wi;
          ai += d1[q] * wi + d2[q] * wr;
          idx += n; if (idx >= 129) idx -= 129;
        }
        const double sc = 1.0 / 129.0;
        float Twr = (float)(ar * sc), Twi = (float)(ai * sc);  // c64 cast
        int e = m * 65 + n;
        float w = W[e];
        float2 p = P[e];
        float Apx = __fadd_rn(__fmul_rn(w, Twr), __fmul_rn(0.05f, p.x));
        float Apy = __fadd_rn(__fmul_rn(w, Twi), __fmul_rn(0.05f, p.y));
        AP[e] = make_float2(Apx, Apy);
        wsf[F_PB + e] = __fadd_rn(__fmul_rn(p.x, Apx), __fmul_rn(p.y, Apy));
      }
    }
    gridbar(cnt, gen);
    // ---- Phase C: block 0 scalar step + vector updates ----
    if (bid == 0){
      for (int i = t; i < M2; i += 256) pb[i] = wsf[F_PB + i];
      __syncthreads();
      pw_tree(pb, T, t);      // pAp
      __syncthreads();
      if (t == 0){
        float rs = wsf[F_RS];
        sh[1] = rs;
        sh[0] = __fdiv_rn(rs, T[0]);   // alpha
      }
      __syncthreads();
      float alpha = sh[0];
      for (int e = t; e < M2; e += 256){
        float2 p = P[e], ap = AP[e], xv = X[e], rv = R[e];
        xv.x = __fadd_rn(xv.x, __fmul_rn(alpha, p.x));
        xv.y = __fadd_rn(xv.y, __fmul_rn(alpha, p.y));
        rv.x = __fsub_rn(rv.x, __fmul_rn(alpha, ap.x));
        rv.y = __fsub_rn(rv.y, __fmul_rn(alpha, ap.y));
        X[e] = xv; R[e] = rv;
        pb[e] = __fadd_rn(__fmul_rn(rv.x, rv.x), __fmul_rn(rv.y, rv.y));
      }
      __syncthreads();
      pw_tree(pb, T, t);      // rsn
      __syncthreads();
      if (t == 0){
        float rsn = T[0];
        sh[0] = __fdiv_rn(rsn, sh[1]);  // beta
        wsf[F_RS] = rsn;
      }
      __syncthreads();
      float beta = sh[0];
      for (int e = t; e < M2; e += 256){
        float2 rv = R[e], p = P[e];
        P[e] = make_float2(__fadd_rn(rv.x, __fmul_rn(beta, p.x)),
                           __fadd_rn(rv.y, __fmul_rn(beta, p.y)));
      }
    }
    gridbar(cnt, gen);
  }
}

__launch_bounds__(256)
__global__ void k_predict(const float* __restrict__ xn, const float* __restrict__ wsf,
                          float* __restrict__ out){
  __shared__ double fbRe[M2];
  __shared__ double fbIm[M2];
  const float hf = wsf[F_H];
  const float* wsq = wsf + F_WS;
  const float2* xb = (const float2*)(wsf + F_X);
  int tid = threadIdx.x;
  for (int i = tid; i < M2; i += 256){
    float w = wsq[i]; float2 q = xb[i];
    fbRe[i] = (double)__fmul_rn(w, q.x);
    fbIm[i] = (double)__fmul_rn(w, q.y);
  }
  __syncthreads();
  int lane = tid & 63;
  int wid = (blockIdx.x * 256 + tid) >> 6;
  int nw = (gridDim.x * 256) >> 6;
  for (int n = wid; n < NTEST; n += nw){
    float hx0 = __fmul_rn(hf, xn[2 * n]);
    float hx1 = __fmul_rn(hf, xn[2 * n + 1]);
    float t0 = __fmul_rn(hx0, (float)(lane - 32));
    float s0, c0; sincosf(__fmul_rn(TPI32, t0), &s0, &c0);
    float t1 = __fmul_rn(hx1, (float)(lane - 32));
    float s1, c1; sincosf(__fmul_rn(TPI32, t1), &s1, &c1);
    float t0x = __fmul_rn(hx0, 32.0f);
    float s0x, c0x; sincosf(__fmul_rn(TPI32, t0x), &s0x, &c0x);
    float t1x = __fmul_rn(hx1, 32.0f);
    float s1x, c1x; sincosf(__fmul_rn(TPI32, t1x), &s1x, &c1x);
    double e0r = (double)c0, e0i = (double)s0;
    double e1r = (double)c1, e1i = (double)s1;
    double gr = 0.0, gi = 0.0;
    for (int a = 0; a < 64; ++a){
      double er = __shfl(e0r, a, 64);
      double ei = __shfl(e0i, a, 64);
      double fr = fbRe[a * 65 + lane];
      double fi = fbIm[a * 65 + lane];
      gr += fr * er - fi * ei;
      gi += fr * ei + fi * er;
    }
    {
      double fr = fbRe[64 * 65 + lane], fi = fbIm[64 * 65 + lane];
      gr += fr * (double)c0x - fi * (double)s0x;
      gi += fr * (double)s0x + fi * (double)c0x;
    }
    double contrib = gr * e1r - gi * e1i;
    {
      double fr = fbRe[lane * 65 + 64], fi = fbIm[lane * 65 + 64];
      double ur = fr * e0r - fi * e0i;
      double ui = fr * e0i + fi * e0r;
      contrib += ur * (double)c1x - ui * (double)s1x;
      if (lane == 0){
        double fr2 = fbRe[64 * 65 + 64], fi2 = fbIm[64 * 65 + 64];
        double vr = fr2 * (double)c0x - fi2 * (double)s0x;
        double vi = fr2 * (double)s0x + fi2 * (double)c0x;
        contrib += vr * (double)c1x - vi * (double)s1x;
      }
    }
    for (int off = 32; off; off >>= 1) contrib += __shfl_xor(contrib, off, 64);
    if (lane == 0) out[n] = (float)contrib;
  }
}

extern "C" void kernel_launch(void* const* d_in, const int* in_sizes, int n_in,
                              void* d_out, int out_size, void* d_ws, size_t ws_size,
                              hipStream_t stream){
  const float* x = (const float*)d_in[0];
  const float* y = (const float*)d_in[1];
  const float* xnew = (const float*)d_in[2];
  float* wsf = (float*)d_ws;
  double* wsd = (double*)d_ws;
  float* out = (float*)d_out;
  unsigned* mm = (unsigned*)(wsf + 4);

  k_init<<<1, 64, 0, stream>>>(mm);
  k_minmax<<<256, 256, 0, stream>>>(x, xnew, mm);
  k_setup<<<1, 256, 0, stream>>>(wsf);
  k_v_main<<<dim3(NCHUNK, 9), 256, 0, stream>>>(x, wsf, wsd + D_VPART);
  k_fk_main<<<dim3(NCHUNK, 5), 256, 0, stream>>>(x, y, wsf, wsd + D_FKPART);
  k_reduce_v<<<33, 256, 0, stream>>>(wsd, wsf);
  k_reduce_fk<<<9, 256, 0, stream>>>(wsd, wsf);
  k_vhat<<<129, 192, 0, stream>>>(wsf);
  k_cg_init<<<17, 256, 0, stream>>>(wsf);
  k_pair0<<<1, 256, 0, stream>>>(wsf);
  k_cgloop<<<129, 256, 0, stream>>>(wsf);
  k_predict<<<256, 256, 0, stream>>>(xnew, wsf, out);
}

// Round 17
// 2949.856 us; speedup vs baseline: 1.0586x; 1.0444x over previous
//
#include <hip/hip_runtime.h>
#include <math.h>

#define M2 4225
#define NTRAIN 100000
#define NTEST 50000
#define CGITERS 30
#define TWO_PI_D 6.283185307179586476925287
#define TPI32 6.28318530717958647692f

// ---- float offsets ----
#define F_H 0
#define F_RS 1
#define F_CNT 2         // software-barrier counter (unsigned)
#define F_GEN 3         // software-barrier generation (unsigned)
// mm encoded uints at floats 4..7
#define F_WS 8          // 4225
#define F_RHS 4234      // 8450 (float2)
#define F_X 12684
#define F_R 21134
#define F_P 29584
#define F_AP 38034
#define F_PB 46484      // 4225 products
#define F_VF 50710      // 129*129 float2 = 33282
#define F_VHAT 83992    // 33282
#define F_PROD 117274   // 33282 (end 150556)
// ---- double offsets ----
#define D_VPART 125330  // 128*16770
#define D_FKPART 2271890 // 128*4290 (end 2821010 dbl = 22.6MB)

#define NCHUNK 128
#define PTSB2 782
#define VHALF 8385
#define VH2 16770
#define FKHALF 2145
#define FH2 4290
#define NBLK 129u

__device__ __forceinline__ unsigned fkey(float f){
  unsigned u = __float_as_uint(f);
  return (u & 0x80000000u) ? ~u : (u | 0x80000000u);
}
__device__ __forceinline__ float fdec(unsigned k){
  unsigned u = (k & 0x80000000u) ? (k & 0x7fffffffu) : ~k;
  return __uint_as_float(u);
}

// ---- LLC-coherent (agent-scope, relaxed) data plumbing: values unchanged ----
__device__ __forceinline__ void st_f2(float2* p, float2 v){
  unsigned long long u = ((unsigned long long)__float_as_uint(v.y) << 32)
                       | (unsigned long long)__float_as_uint(v.x);
  __hip_atomic_store((unsigned long long*)p, u, __ATOMIC_RELAXED, __HIP_MEMORY_SCOPE_AGENT);
}
__device__ __forceinline__ float2 ld_f2(const float2* p){
  unsigned long long u = __hip_atomic_load((const unsigned long long*)p,
                                           __ATOMIC_RELAXED, __HIP_MEMORY_SCOPE_AGENT);
  return make_float2(__uint_as_float((unsigned)u), __uint_as_float((unsigned)(u >> 32)));
}
__device__ __forceinline__ void st_f(float* p, float v){
  __hip_atomic_store(p, v, __ATOMIC_RELAXED, __HIP_MEMORY_SCOPE_AGENT);
}
__device__ __forceinline__ float ld_f(const float* p){
  return __hip_atomic_load(p, __ATOMIC_RELAXED, __HIP_MEMORY_SCOPE_AGENT);
}

__global__ void k_init(unsigned* mm){
  if (threadIdx.x == 0){
    mm[0] = 0xFFFFFFFFu; mm[1] = 0u; mm[2] = 0xFFFFFFFFu; mm[3] = 0u;
  }
}

__global__ void k_minmax(const float* __restrict__ x, const float* __restrict__ xn,
                         unsigned* __restrict__ mm){
  int tid = blockIdx.x * blockDim.x + threadIdx.x;
  int str = gridDim.x * blockDim.x;
  float mn0 = 1e30f, mx0 = -1e30f, mn1 = 1e30f, mx1 = -1e30f;
  const float2* a = (const float2*)x;
  for (int i = tid; i < NTRAIN; i += str){
    float2 v = a[i];
    mn0 = fminf(mn0, v.x); mx0 = fmaxf(mx0, v.x);
    mn1 = fminf(mn1, v.y); mx1 = fmaxf(mx1, v.y);
  }
  const float2* b = (const float2*)xn;
  for (int i = tid; i < NTEST; i += str){
    float2 v = b[i];
    mn0 = fminf(mn0, v.x); mx0 = fmaxf(mx0, v.x);
    mn1 = fminf(mn1, v.y); mx1 = fmaxf(mx1, v.y);
  }
  for (int off = 32; off; off >>= 1){
    mn0 = fminf(mn0, __shfl_xor(mn0, off, 64));
    mx0 = fmaxf(mx0, __shfl_xor(mx0, off, 64));
    mn1 = fminf(mn1, __shfl_xor(mn1, off, 64));
    mx1 = fmaxf(mx1, __shfl_xor(mx1, off, 64));
  }
  if ((threadIdx.x & 63) == 0){
    atomicMin(&mm[0], fkey(mn0)); atomicMax(&mm[1], fkey(mx0));
    atomicMin(&mm[2], fkey(mn1)); atomicMax(&mm[3], fkey(mx1));
  }
}

__global__ void k_setup(float* __restrict__ wsf){
  const unsigned* mm = (const unsigned*)(wsf + 4);
  float mn0 = fdec(mm[0]), mx0 = fdec(mm[1]);
  float mn1 = fdec(mm[2]), mx1 = fdec(mm[3]);
  float d0 = __fsub_rn(mx0, mn0), d1 = __fsub_rn(mx1, mn1);
  float L = fmaxf(d0, d1);
  if (L <= 1e-9f) L = 1.0f;
  float hf = __fdiv_rn(1.0f, L);
  if (threadIdx.x == 0) wsf[F_H] = hf;
  const float c0f = (float)(TWO_PI_D * 0.01);
  const float c1f = (float)(-2.0 * 9.869604401089358618834 * 0.01);
  float h2f = __fmul_rn(hf, hf);
  for (int e = threadIdx.x; e < M2; e += blockDim.x){
    int r = e / 65, c = e - r * 65;
    float xi0 = __fmul_rn(hf, (float)(r - 32));
    float xi1 = __fmul_rn(hf, (float)(c - 32));
    float sq = __fadd_rn(__fmul_rn(xi0, xi0), __fmul_rn(xi1, xi1));
    float spec = __fmul_rn(c0f, expf(__fmul_rn(c1f, sq)));
    wsf[F_WS + e] = sqrtf(__fmul_rn(spec, h2f));
  }
}

// v[o0, j]: o0 in [0,65), j in [0,129) (col offset j-64)
// grid (NCHUNK, 9): y = 16-column tile. acc[5] double2 per thread (no spill).
__launch_bounds__(256)
__global__ void k_v_main(const float* __restrict__ x, const float* __restrict__ wsf,
                         double* __restrict__ vpart){
  __shared__ float2 aL[16][80];
  __shared__ float2 bL[16][16];
  __shared__ float hxs[16][2];
  const float hf = wsf[F_H];
  const int tid = threadIdx.x;
  const int t0 = tid >> 4, t1 = tid & 15;
  const int jcol = blockIdx.y * 16 + t1;   // 0..143 (valid < 129)
  double2 acc[5];
  #pragma unroll
  for (int k = 0; k < 5; ++k) acc[k] = make_double2(0.0, 0.0);
  const int p0 = blockIdx.x * PTSB2;
  const int pend = min(p0 + PTSB2, NTRAIN);
  for (int base = p0; base < pend; base += 16){
    if (tid < 32){
      int p = tid >> 1, d = tid & 1;
      int gp = base + p;
      hxs[p][d] = (gp < pend) ? __fmul_rn(hf, x[2 * gp + d]) : 0.f;
    }
    __syncthreads();
    for (int i = tid; i < 16 * 80; i += 256){
      int p = i / 80;
      int o = i - p * 80;
      int gp = base + p;
      float2 va = make_float2(0.f, 0.f);
      if (gp < pend && o < 65){
        float t = __fmul_rn(hxs[p][0], (float)o);
        float sn, cs; sincosf(__fmul_rn(TPI32, t), &sn, &cs);
        va = make_float2(cs, -sn);
      }
      aL[p][o] = va;
    }
    {
      int p = t0, c = t1;
      int gp = base + p;
      int j = blockIdx.y * 16 + c;
      float2 vb = make_float2(0.f, 0.f);
      if (gp < pend && j < 129){
        float t = __fmul_rn(hxs[p][1], (float)(j - 64));
        float sn, cs; sincosf(__fmul_rn(TPI32, t), &sn, &cs);
        vb = make_float2(cs, -sn);
      }
      bL[p][c] = vb;
    }
    __syncthreads();
    #pragma unroll 1
    for (int p = 0; p < 16; ++p){
      float2 bv = bL[p][t1];
      float2 av[5];
      #pragma unroll
      for (int k = 0; k < 5; ++k) av[k] = aL[p][t0 + 16 * k];
      #pragma unroll
      for (int k = 0; k < 5; ++k){
        acc[k].x += (double)av[k].x * (double)bv.x - (double)av[k].y * (double)bv.y;
        acc[k].y += (double)av[k].x * (double)bv.y + (double)av[k].y * (double)bv.x;
      }
    }
    __syncthreads();
  }
  double* outp = vpart + (size_t)blockIdx.x * VH2;
  if (jcol < 129){
    #pragma unroll
    for (int k = 0; k < 5; ++k){
      int o0 = t0 + 16 * k;
      if (o0 < 65){
        int e = o0 * 129 + jcol;
        outp[2 * e] = acc[k].x;
        outp[2 * e + 1] = acc[k].y;
      }
    }
  }
}

// fk[o, c]: o in [0,33), c in [0,65) (freq c-32); grid (NCHUNK, 5)
__launch_bounds__(256)
__global__ void k_fk_main(const float* __restrict__ x, const float* __restrict__ y,
                          const float* __restrict__ wsf, double* __restrict__ fkpart){
  __shared__ float2 aL[16][48];
  __shared__ float2 bL[16][16];
  __shared__ float hxs[16][2];
  __shared__ float ys[16];
  const float hf = wsf[F_H];
  const int tid = threadIdx.x;
  const int t0 = tid >> 4, t1 = tid & 15;
  const int jcol = blockIdx.y * 16 + t1;   // 0..79 (valid < 65)
  double2 acc[3];
  #pragma unroll
  for (int k = 0; k < 3; ++k) acc[k] = make_double2(0.0, 0.0);
  const int p0 = blockIdx.x * PTSB2;
  const int pend = min(p0 + PTSB2, NTRAIN);
  for (int base = p0; base < pend; base += 16){
    if (tid < 32){
      int p = tid >> 1, d = tid & 1;
      int gp = base + p;
      hxs[p][d] = (gp < pend) ? __fmul_rn(hf, x[2 * gp + d]) : 0.f;
    } else if (tid < 48){
      int p = tid - 32;
      int gp = base + p;
      ys[p] = (gp < pend) ? y[gp] : 0.f;
    }
    __syncthreads();
    for (int i = tid; i < 16 * 48; i += 256){
      int p = i / 48, o = i - p * 48;
      int gp = base + p;
      float2 val = make_float2(0.f, 0.f);
      if (o < 33 && gp < pend){
        float t = __fmul_rn(hxs[p][0], (float)o);
        float sn, cs; sincosf(__fmul_rn(TPI32, t), &sn, &cs);
        val = make_float2(__fmul_rn(ys[p], cs), __fmul_rn(ys[p], -sn));
      }
      aL[p][o] = val;
    }
    {
      int p = t0, c = t1;
      int gp = base + p;
      int j = blockIdx.y * 16 + c;
      float2 vb = make_float2(0.f, 0.f);
      if (gp < pend && j < 65){
        float t = __fmul_rn(hxs[p][1], (float)(j - 32));
        float sn, cs; sincosf(__fmul_rn(TPI32, t), &sn, &cs);
        vb = make_float2(cs, -sn);
      }
      bL[p][c] = vb;
    }
    __syncthreads();
    #pragma unroll 1
    for (int p = 0; p < 16; ++p){
      float2 bv = bL[p][t1];
      float2 av[3];
      #pragma unroll
      for (int k = 0; k < 3; ++k) av[k] = aL[p][t0 + 16 * k];
      #pragma unroll
      for (int k = 0; k < 3; ++k){
        acc[k].x += (double)av[k].x * (double)bv.x - (double)av[k].y * (double)bv.y;
        acc[k].y += (double)av[k].x * (double)bv.y + (double)av[k].y * (double)bv.x;
      }
    }
    __syncthreads();
  }
  double* outp = fkpart + (size_t)blockIdx.x * FH2;
  if (jcol < 65){
    #pragma unroll
    for (int k = 0; k < 3; ++k){
      int o0 = t0 + 16 * k;
      if (o0 < 33){
        int e = o0 * 65 + jcol;
        outp[2 * e] = acc[k].x;
        outp[2 * e + 1] = acc[k].y;
      }
    }
  }
}

__global__ void k_reduce_v(const double* __restrict__ wsd, float* __restrict__ wsf){
  int e = blockIdx.x * blockDim.x + threadIdx.x;
  if (e >= VHALF) return;
  const double* vp = wsd + D_VPART;
  double sr = 0.0, si = 0.0;
  for (int k = 0; k < NCHUNK; ++k){
    sr += vp[(size_t)k * VH2 + 2 * e];
    si += vp[(size_t)k * VH2 + 2 * e + 1];
  }
  float r32 = (float)sr, i32 = (float)si;
  int o0 = e / 129, j = e - o0 * 129;
  float2* vF = (float2*)(wsf + F_VF);
  vF[(o0 + 64) * 129 + j] = make_float2(r32, i32);
  if (o0 > 0) vF[(64 - o0) * 129 + (128 - j)] = make_float2(r32, -i32);
}

__global__ void k_reduce_fk(const double* __restrict__ wsd, float* __restrict__ wsf){
  int e = blockIdx.x * blockDim.x + threadIdx.x;
  if (e >= FKHALF) return;
  const double* fp = wsd + D_FKPART;
  double sr = 0.0, si = 0.0;
  for (int k = 0; k < NCHUNK; ++k){
    sr += fp[(size_t)k * FH2 + 2 * e];
    si += fp[(size_t)k * FH2 + 2 * e + 1];
  }
  float fr = (float)sr, fi = (float)si;
  int a = e / 65, c = e - a * 65;
  int ef = (a + 32) * 65 + c;
  float wf = wsf[F_WS + ef];
  float* rhs = wsf + F_RHS;
  rhs[2 * ef] = __fmul_rn(wf, fr);
  rhs[2 * ef + 1] = __fmul_rn(wf, fi);
  if (a > 0){
    int ef2 = (32 - a) * 65 + (64 - c);
    float wf2 = wsf[F_WS + ef2];
    rhs[2 * ef2] = __fmul_rn(wf2, fr);
    rhs[2 * ef2 + 1] = -__fmul_rn(wf2, fi);
  }
}

// fused vhat: block p computes T1 row p (f64) then vhat row p (c64)
__launch_bounds__(192)
__global__ void k_vhat(float* __restrict__ wsf){
  __shared__ double twc[129], tws[129];
  __shared__ double t1r[129], t1i[129];
  int p = blockIdx.x, t = threadIdx.x;
  if (t < 129){
    double ang = TWO_PI_D * (double)t / 129.0;
    double s, c; sincos(ang, &s, &c);
    twc[t] = c; tws[t] = s;
  }
  __syncthreads();
  if (t < 129){
    const float2* vF = (const float2*)(wsf + F_VF);
    int n = t;
    int nsrc = (n + 64) % 129;
    double ar = 0.0, ai = 0.0;
    for (int m = 0; m < 129; ++m){
      float2 v = vF[((m + 64) % 129) * 129 + nsrc];
      int idx = (p * m) % 129;
      double wr = twc[idx], wi = -tws[idx];
      ar += (double)v.x * wr - (double)v.y * wi;
      ai += (double)v.x * wi + (double)v.y * wr;
    }
    t1r[n] = ar; t1i[n] = ai;
  }
  __syncthreads();
  if (t < 129){
    int q = t;
    double ar = 0.0, ai = 0.0;
    for (int n = 0; n < 129; ++n){
      int idx = (q * n) % 129;
      double wr = twc[idx], wi = -tws[idx];
      ar += t1r[n] * wr - t1i[n] * wi;
      ai += t1r[n] * wi + t1i[n] * wr;
    }
    ((float2*)(wsf + F_VHAT))[p * 129 + q] = make_float2((float)ar, (float)ai);
  }
}

__global__ void k_cg_init(float* __restrict__ wsf){
  int e = blockIdx.x * blockDim.x + threadIdx.x;
  if (e == 0){
    ((unsigned*)wsf)[F_CNT] = 0u;
    ((unsigned*)wsf)[F_GEN] = 0u;
  }
  if (e >= M2) return;
  const float2* rhs = (const float2*)(wsf + F_RHS);
  float2 b = rhs[e];
  ((float2*)(wsf + F_X))[e] = make_float2(0.f, 0.f);
  ((float2*)(wsf + F_R))[e] = b;
  ((float2*)(wsf + F_P))[e] = b;
  wsf[F_PB + e] = __fadd_rn(__fmul_rn(b.x, b.x), __fmul_rn(b.y, b.y));
}

// ---- numpy pairwise sum (exact replication), n = 4225 ----
__device__ __forceinline__ float pw_leaf(const float* d, int o, int n){
  float r0 = d[o], r1 = d[o+1], r2 = d[o+2], r3 = d[o+3];
  float r4 = d[o+4], r5 = d[o+5], r6 = d[o+6], r7 = d[o+7];
  int i = 8;
  int lim = n - (n & 7);
  for (; i < lim; i += 8){
    r0 = __fadd_rn(r0, d[o+i]);   r1 = __fadd_rn(r1, d[o+i+1]);
    r2 = __fadd_rn(r2, d[o+i+2]); r3 = __fadd_rn(r3, d[o+i+3]);
    r4 = __fadd_rn(r4, d[o+i+4]); r5 = __fadd_rn(r5, d[o+i+5]);
    r6 = __fadd_rn(r6, d[o+i+6]); r7 = __fadd_rn(r7, d[o+i+7]);
  }
  float res = __fadd_rn(__fadd_rn(__fadd_rn(r0, r1), __fadd_rn(r2, r3)),
                        __fadd_rn(__fadd_rn(r4, r5), __fadd_rn(r6, r7)));
  for (; i < n; ++i) res = __fadd_rn(res, d[o+i]);
  return res;
}

__device__ __forceinline__ void pw_tree(const float* pb, float* T, int tid){
  if (tid < 16){
    const int tb[16] = {0,264,528,792,1056,1320,1584,1848,
                        2112,2376,2640,2904,3168,3432,3696,3960};
    int base = tb[tid];
    int sz3 = (tid == 15) ? 73 : 72;
    float L0 = pw_leaf(pb, base, 128);
    float L1 = pw_leaf(pb, base + 128, 64);
    float L2 = pw_leaf(pb, base + 192, sz3);
    T[tid] = __fadd_rn(L0, __fadd_rn(L1, L2));
  }
  __syncthreads();
  if (tid == 0){
    float s0 = __fadd_rn(__fadd_rn(T[0], T[1]), __fadd_rn(T[2], T[3]));
    float s1 = __fadd_rn(__fadd_rn(T[4], T[5]), __fadd_rn(T[6], T[7]));
    float s2 = __fadd_rn(__fadd_rn(T[8], T[9]), __fadd_rn(T[10], T[11]));
    float s3 = __fadd_rn(__fadd_rn(T[12], T[13]), __fadd_rn(T[14], T[15]));
    T[0] = __fadd_rn(__fadd_rn(s0, s1), __fadd_rn(s2, s3));
  }
}

__launch_bounds__(256)
__global__ void k_pair0(float* __restrict__ wsf){
  __shared__ float pb[M2];
  __shared__ float T[16];
  int tid = threadIdx.x;
  for (int i = tid; i < M2; i += 256) pb[i] = wsf[F_PB + i];
  __syncthreads();
  pw_tree(pb, T, tid);
  __syncthreads();
  if (tid == 0) wsf[F_RS] = T[0];
}

// Fence-free software grid barrier. All cross-block data moves via agent-scope
// (sc1 / LLC) relaxed atomics, so no L2 writeback/invalidate is needed here.
// __syncthreads() before arrival drains vmcnt(0) -> sc1 stores are LLC-visible.
// Consuming the exchange return value orders cnt-reset before gen-bump.
__device__ __forceinline__ void gridbar(unsigned* cnt, unsigned* gen){
  __syncthreads();
  if (threadIdx.x == 0){
    unsigned g = __hip_atomic_load(gen, __ATOMIC_RELAXED, __HIP_MEMORY_SCOPE_AGENT);
    unsigned old = __hip_atomic_fetch_add(cnt, 1u, __ATOMIC_RELAXED, __HIP_MEMORY_SCOPE_AGENT);
    if (old == NBLK - 1u){
      unsigned prev = __hip_atomic_exchange(cnt, 0u, __ATOMIC_RELAXED, __HIP_MEMORY_SCOPE_AGENT);
      if (prev != 0xFFFFFFFFu)   // always true; forces wait on the exchange
        __hip_atomic_fetch_add(gen, 1u, __ATOMIC_RELAXED, __HIP_MEMORY_SCOPE_AGENT);
    } else {
      int guard = 0;
      while (__hip_atomic_load(gen, __ATOMIC_RELAXED, __HIP_MEMORY_SCOPE_AGENT) == g){
        __builtin_amdgcn_s_sleep(2);
        if (++guard > (1 << 20)) break;   // safety: fail loudly instead of hang
      }
    }
  }
  __syncthreads();
}

// ---- the entire 30-iteration CG loop as ONE plain kernel (129 blocks) ----
// Phase A (wfft+vhat-mul): all 129 blocks. Phase B (ifft+Ap+pb): blocks 0..64.
// Phase C (scalars+updates): block 0. FP arithmetic verbatim from R13 kernels;
// cross-block data via sc1 atomics (bit-identical values).
__launch_bounds__(256)
__global__ void k_cgloop(float* __restrict__ wsf){
  __shared__ double twc[129], tws[129];
  __shared__ double d1[129], d2[129];
  __shared__ float pb[M2];
  __shared__ float T[16];
  __shared__ float sh[2];
  const int bid = blockIdx.x;
  const int t = threadIdx.x;
  unsigned* cnt = ((unsigned*)wsf) + F_CNT;
  unsigned* gen = ((unsigned*)wsf) + F_GEN;
  if (t < 129){
    double ang = TWO_PI_D * (double)t / 129.0;
    double s, c; sincos(ang, &s, &c);
    twc[t] = c; tws[t] = s;
  }
  __syncthreads();
  float2* PROD = (float2*)(wsf + F_PROD);
  const float2* VHAT = (const float2*)(wsf + F_VHAT);
  float2* X = (float2*)(wsf + F_X);
  float2* R = (float2*)(wsf + F_R);
  float2* P = (float2*)(wsf + F_P);
  float2* AP = (float2*)(wsf + F_AP);
  const float* W = wsf + F_WS;

  for (int it = 0; it < CGITERS; ++it){
    // ---- Phase A: block pr=bid computes PROD row pr ----
    {
      const int pr = bid;
      if (t < 65){
        int n = t;
        double ar = 0.0, ai = 0.0;
        int idx = 0;
        for (int m = 0; m < 65; ++m){
          int e = m * 65 + n;
          float2 p = ld_f2(&P[e]);
          float w = W[e];
          float wbr = __fmul_rn(w, p.x), wbi = __fmul_rn(w, p.y);
          double wr = twc[idx], wi = -tws[idx];
          ar += (double)wbr * wr - (double)wbi * wi;
          ai += (double)wbr * wi + (double)wbi * wr;
          idx += pr; if (idx >= 129) idx -= 129;
        }
        d1[n] = ar; d2[n] = ai;
      }
      __syncthreads();
      if (t < 129){
        int q = t;
        double ar = 0.0, ai = 0.0;
        int idx = 0;
        for (int n = 0; n < 65; ++n){
          double wr = twc[idx], wi = -tws[idx];
          ar += d1[n] * wr - d2[n] * wi;
          ai += d1[n] * wi + d2[n] * wr;
          idx += q; if (idx >= 129) idx -= 129;
        }
        float Wr = (float)ar, Wi = (float)ai;   // c64 cast of fftn output
        float2 v = VHAT[pr * 129 + q];
        float prre = __fsub_rn(__fmul_rn(v.x, Wr), __fmul_rn(v.y, Wi));
        float prim = __fadd_rn(__fmul_rn(v.x, Wi), __fmul_rn(v.y, Wr));
        st_f2(&PROD[pr * 129 + q], make_float2(prre, prim));
      }
    }
    gridbar(cnt, gen);
    // ---- Phase B: blocks m=bid<65 compute Ap row m ----
    if (bid < 65){
      const int m = bid;
      if (t < 129){
        int q = t;
        double ar = 0.0, ai = 0.0;
        int idx = 0;
        for (int pr = 0; pr < 129; ++pr){
          float2 v = ld_f2(&PROD[pr * 129 + q]);
          double wr = twc[idx], wi = tws[idx];   // e^{+i}
          ar += (double)v.x * wr - (double)v.y * wi;
          ai += (double)v.x * wi + (double)v.y * wr;
          idx += m; if (idx >= 129) idx -= 129;
        }
        const double sc = 1.0 / 129.0;
        d1[q] = ar * sc; d2[q] = ai * sc;
      }
      __syncthreads();
      if (t < 65){
        int n = t;
        double ar = 0.0, ai = 0.0;
        int idx = 0;
        for (int q = 0; q < 129; ++q){
          double wr = twc[idx], wi = tws[idx];   // e^{+i}
          ar += d1[q] * wr - d2[q] * wi;
          ai += d1[q] * wi + d2[q] * wr;
          idx += n; if (idx >= 129) idx -= 129;
        }
        const double sc = 1.0 / 129.0;
        float Twr = (float)(ar * sc), Twi = (float)(ai * sc);  // c64 cast
        int e = m * 65 + n;
        float w = W[e];
        float2 p = ld_f2(&P[e]);
        float Apx = __fadd_rn(__fmul_rn(w, Twr), __fmul_rn(0.05f, p.x));
        float Apy = __fadd_rn(__fmul_rn(w, Twi), __fmul_rn(0.05f, p.y));
        st_f2(&AP[e], make_float2(Apx, Apy));
        st_f(&wsf[F_PB + e], __fadd_rn(__fmul_rn(p.x, Apx), __fmul_rn(p.y, Apy)));
      }
    }
    gridbar(cnt, gen);
    // ---- Phase C: block 0 scalar step + vector updates ----
    if (bid == 0){
      for (int i = t; i < M2; i += 256) pb[i] = ld_f(&wsf[F_PB + i]);
      __syncthreads();
      pw_tree(pb, T, t);      // pAp
      __syncthreads();
      if (t == 0){
        float rs = wsf[F_RS];
        sh[1] = rs;
        sh[0] = __fdiv_rn(rs, T[0]);   // alpha
      }
      __syncthreads();
      float alpha = sh[0];
      for (int e = t; e < M2; e += 256){
        float2 p = ld_f2(&P[e]);
        float2 ap = ld_f2(&AP[e]);
        float2 xv = X[e], rv = R[e];
        xv.x = __fadd_rn(xv.x, __fmul_rn(alpha, p.x));
        xv.y = __fadd_rn(xv.y, __fmul_rn(alpha, p.y));
        rv.x = __fsub_rn(rv.x, __fmul_rn(alpha, ap.x));
        rv.y = __fsub_rn(rv.y, __fmul_rn(alpha, ap.y));
        X[e] = xv; R[e] = rv;
        pb[e] = __fadd_rn(__fmul_rn(rv.x, rv.x), __fmul_rn(rv.y, rv.y));
      }
      __syncthreads();
      pw_tree(pb, T, t);      // rsn
      __syncthreads();
      if (t == 0){
        float rsn = T[0];
        sh[0] = __fdiv_rn(rsn, sh[1]);  // beta
        wsf[F_RS] = rsn;
      }
      __syncthreads();
      float beta = sh[0];
      for (int e = t; e < M2; e += 256){
        float2 rv = R[e];
        float2 p = ld_f2(&P[e]);
        st_f2(&P[e], make_float2(__fadd_rn(rv.x, __fmul_rn(beta, p.x)),
                                 __fadd_rn(rv.y, __fmul_rn(beta, p.y))));
      }
    }
    gridbar(cnt, gen);
  }
}

__launch_bounds__(256)
__global__ void k_predict(const float* __restrict__ xn, const float* __restrict__ wsf,
                          float* __restrict__ out){
  __shared__ double fbRe[M2];
  __shared__ double fbIm[M2];
  const float hf = wsf[F_H];
  const float* wsq = wsf + F_WS;
  const float2* xb = (const float2*)(wsf + F_X);
  int tid = threadIdx.x;
  for (int i = tid; i < M2; i += 256){
    float w = wsq[i]; float2 q = xb[i];
    fbRe[i] = (double)__fmul_rn(w, q.x);
    fbIm[i] = (double)__fmul_rn(w, q.y);
  }
  __syncthreads();
  int lane = tid & 63;
  int wid = (blockIdx.x * 256 + tid) >> 6;
  int nw = (gridDim.x * 256) >> 6;
  for (int n = wid; n < NTEST; n += nw){
    float hx0 = __fmul_rn(hf, xn[2 * n]);
    float hx1 = __fmul_rn(hf, xn[2 * n + 1]);
    float t0 = __fmul_rn(hx0, (float)(lane - 32));
    float s0, c0; sincosf(__fmul_rn(TPI32, t0), &s0, &c0);
    float t1 = __fmul_rn(hx1, (float)(lane - 32));
    float s1, c1; sincosf(__fmul_rn(TPI32, t1), &s1, &c1);
    float t0x = __fmul_rn(hx0, 32.0f);
    float s0x, c0x; sincosf(__fmul_rn(TPI32, t0x), &s0x, &c0x);
    float t1x = __fmul_rn(hx1, 32.0f);
    float s1x, c1x; sincosf(__fmul_rn(TPI32, t1x), &s1x, &c1x);
    double e0r = (double)c0, e0i = (double)s0;
    double e1r = (double)c1, e1i = (double)s1;
    double gr = 0.0, gi = 0.0;
    for (int a = 0; a < 64; ++a){
      double er = __shfl(e0r, a, 64);
      double ei = __shfl(e0i, a, 64);
      double fr = fbRe[a * 65 + lane];
      double fi = fbIm[a * 65 + lane];
      gr += fr * er - fi * ei;
      gi += fr * ei + fi * er;
    }
    {
      double fr = fbRe[64 * 65 + lane], fi = fbIm[64 * 65 + lane];
      gr += fr * (double)c0x - fi * (double)s0x;
      gi += fr * (double)s0x + fi * (double)c0x;
    }
    double contrib = gr * e1r - gi * e1i;
    {
      double fr = fbRe[lane * 65 + 64], fi = fbIm[lane * 65 + 64];
      double ur = fr * e0r - fi * e0i;
      double ui = fr * e0i + fi * e0r;
      contrib += ur * (double)c1x - ui * (double)s1x;
      if (lane == 0){
        double fr2 = fbRe[64 * 65 + 64], fi2 = fbIm[64 * 65 + 64];
        double vr = fr2 * (double)c0x - fi2 * (double)s0x;
        double vi = fr2 * (double)s0x + fi2 * (double)c0x;
        contrib += vr * (double)c1x - vi * (double)s1x;
      }
    }
    for (int off = 32; off; off >>= 1) contrib += __shfl_xor(contrib, off, 64);
    if (lane == 0) out[n] = (float)contrib;
  }
}

extern "C" void kernel_launch(void* const* d_in, const int* in_sizes, int n_in,
                              void* d_out, int out_size, void* d_ws, size_t ws_size,
                              hipStream_t stream){
  const float* x = (const float*)d_in[0];
  const float* y = (const float*)d_in[1];
  const float* xnew = (const float*)d_in[2];
  float* wsf = (float*)d_ws;
  double* wsd = (double*)d_ws;
  float* out = (float*)d_out;
  unsigned* mm = (unsigned*)(wsf + 4);

  k_init<<<1, 64, 0, stream>>>(mm);
  k_minmax<<<256, 256, 0, stream>>>(x, xnew, mm);
  k_setup<<<1, 256, 0, stream>>>(wsf);
  k_v_main<<<dim3(NCHUNK, 9), 256, 0, stream>>>(x, wsf, wsd + D_VPART);
  k_fk_main<<<dim3(NCHUNK, 5), 256, 0, stream>>>(x, y, wsf, wsd + D_FKPART);
  k_reduce_v<<<33, 256, 0, stream>>>(wsd, wsf);
  k_reduce_fk<<<9, 256, 0, stream>>>(wsd, wsf);
  k_vhat<<<129, 192, 0, stream>>>(wsf);
  k_cg_init<<<17, 256, 0, stream>>>(wsf);
  k_pair0<<<1, 256, 0, stream>>>(wsf);
  k_cgloop<<<129, 256, 0, stream>>>(wsf);
  k_predict<<<256, 256, 0, stream>>>(xnew, wsf, out);
}

// Round 18
// 2282.918 us; speedup vs baseline: 1.3678x; 1.2921x over previous
//
#include <hip/hip_runtime.h>
#include <math.h>

#define M2 4225
#define NTRAIN 100000
#define NTEST 50000
#define CGITERS 30
#define TWO_PI_D 6.283185307179586476925287
#define TPI32 6.28318530717958647692f

// ---- float offsets ----
#define F_H 0
#define F_RS 1
#define F_PAP 2
#define F_RSN 3
// mm encoded uints at floats 4..7
#define F_WS 8          // 4225
#define F_RHS 4234      // 8450 (float2)
#define F_X 12684
#define F_R 21134
#define F_P 29584
#define F_AP 38034
#define F_PB 46484      // 4225 products
#define F_VF 50710      // 129*129 float2 = 33282
#define F_VHAT 83992    // 33282
#define F_PROD 117274   // 33282 (end 150556)
// ---- double offsets ----
#define D_VPART 125330  // 128*16770
#define D_FKPART 2271890 // 128*4290 (end 2821010 dbl = 22.6MB)

#define NCHUNK 128
#define PTSB2 782
#define VHALF 8385
#define VH2 16770
#define FKHALF 2145
#define FH2 4290
#define NB_APPLY 529

__device__ __forceinline__ unsigned fkey(float f){
  unsigned u = __float_as_uint(f);
  return (u & 0x80000000u) ? ~u : (u | 0x80000000u);
}
__device__ __forceinline__ float fdec(unsigned k){
  unsigned u = (k & 0x80000000u) ? (k & 0x7fffffffu) : ~k;
  return __uint_as_float(u);
}

__global__ void k_init(unsigned* mm){
  if (threadIdx.x == 0){
    mm[0] = 0xFFFFFFFFu; mm[1] = 0u; mm[2] = 0xFFFFFFFFu; mm[3] = 0u;
  }
}

__global__ void k_minmax(const float* __restrict__ x, const float* __restrict__ xn,
                         unsigned* __restrict__ mm){
  int tid = blockIdx.x * blockDim.x + threadIdx.x;
  int str = gridDim.x * blockDim.x;
  float mn0 = 1e30f, mx0 = -1e30f, mn1 = 1e30f, mx1 = -1e30f;
  const float2* a = (const float2*)x;
  for (int i = tid; i < NTRAIN; i += str){
    float2 v = a[i];
    mn0 = fminf(mn0, v.x); mx0 = fmaxf(mx0, v.x);
    mn1 = fminf(mn1, v.y); mx1 = fmaxf(mx1, v.y);
  }
  const float2* b = (const float2*)xn;
  for (int i = tid; i < NTEST; i += str){
    float2 v = b[i];
    mn0 = fminf(mn0, v.x); mx0 = fmaxf(mx0, v.x);
    mn1 = fminf(mn1, v.y); mx1 = fmaxf(mx1, v.y);
  }
  for (int off = 32; off; off >>= 1){
    mn0 = fminf(mn0, __shfl_xor(mn0, off, 64));
    mx0 = fmaxf(mx0, __shfl_xor(mx0, off, 64));
    mn1 = fminf(mn1, __shfl_xor(mn1, off, 64));
    mx1 = fmaxf(mx1, __shfl_xor(mx1, off, 64));
  }
  if ((threadIdx.x & 63) == 0){
    atomicMin(&mm[0], fkey(mn0)); atomicMax(&mm[1], fkey(mx0));
    atomicMin(&mm[2], fkey(mn1)); atomicMax(&mm[3], fkey(mx1));
  }
}

__global__ void k_setup(float* __restrict__ wsf){
  const unsigned* mm = (const unsigned*)(wsf + 4);
  float mn0 = fdec(mm[0]), mx0 = fdec(mm[1]);
  float mn1 = fdec(mm[2]), mx1 = fdec(mm[3]);
  float d0 = __fsub_rn(mx0, mn0), d1 = __fsub_rn(mx1, mn1);
  float L = fmaxf(d0, d1);
  if (L <= 1e-9f) L = 1.0f;
  float hf = __fdiv_rn(1.0f, L);
  if (threadIdx.x == 0) wsf[F_H] = hf;
  const float c0f = (float)(TWO_PI_D * 0.01);
  const float c1f = (float)(-2.0 * 9.869604401089358618834 * 0.01);
  float h2f = __fmul_rn(hf, hf);
  for (int e = threadIdx.x; e < M2; e += blockDim.x){
    int r = e / 65, c = e - r * 65;
    float xi0 = __fmul_rn(hf, (float)(r - 32));
    float xi1 = __fmul_rn(hf, (float)(c - 32));
    float sq = __fadd_rn(__fmul_rn(xi0, xi0), __fmul_rn(xi1, xi1));
    float spec = __fmul_rn(c0f, expf(__fmul_rn(c1f, sq)));
    wsf[F_WS + e] = sqrtf(__fmul_rn(spec, h2f));
  }
}

// v[o0, j]: o0 in [0,65), j in [0,129) (col offset j-64)
// grid (NCHUNK, 9). Phases pre-converted to double2 in LDS (cvt hoisted out
// of the MAC loop); accumulation arithmetic identical to the passing R13.
__launch_bounds__(256)
__global__ void k_v_main(const float* __restrict__ x, const float* __restrict__ wsf,
                         double* __restrict__ vpart){
  __shared__ double2 aL[16][80];
  __shared__ double2 bL[16][16];
  __shared__ float hxs[16][2];
  const float hf = wsf[F_H];
  const int tid = threadIdx.x;
  const int t0 = tid >> 4, t1 = tid & 15;
  const int jcol = blockIdx.y * 16 + t1;   // 0..143 (valid < 129)
  double2 acc[5];
  #pragma unroll
  for (int k = 0; k < 5; ++k) acc[k] = make_double2(0.0, 0.0);
  const int p0 = blockIdx.x * PTSB2;
  const int pend = min(p0 + PTSB2, NTRAIN);
  for (int base = p0; base < pend; base += 16){
    if (tid < 32){
      int p = tid >> 1, d = tid & 1;
      int gp = base + p;
      hxs[p][d] = (gp < pend) ? __fmul_rn(hf, x[2 * gp + d]) : 0.f;
    }
    __syncthreads();
    for (int i = tid; i < 16 * 80; i += 256){
      int p = i / 80;
      int o = i - p * 80;
      int gp = base + p;
      double2 va = make_double2(0.0, 0.0);
      if (gp < pend && o < 65){
        float t = __fmul_rn(hxs[p][0], (float)o);
        float sn, cs; sincosf(__fmul_rn(TPI32, t), &sn, &cs);
        va = make_double2((double)cs, (double)(-sn));
      }
      aL[p][o] = va;
    }
    {
      int p = t0, c = t1;
      int gp = base + p;
      int j = blockIdx.y * 16 + c;
      double2 vb = make_double2(0.0, 0.0);
      if (gp < pend && j < 129){
        float t = __fmul_rn(hxs[p][1], (float)(j - 64));
        float sn, cs; sincosf(__fmul_rn(TPI32, t), &sn, &cs);
        vb = make_double2((double)cs, (double)(-sn));
      }
      bL[p][c] = vb;
    }
    __syncthreads();
    #pragma unroll 1
    for (int p = 0; p < 16; ++p){
      double2 bv = bL[p][t1];
      double2 av[5];
      #pragma unroll
      for (int k = 0; k < 5; ++k) av[k] = aL[p][t0 + 16 * k];
      #pragma unroll
      for (int k = 0; k < 5; ++k){
        acc[k].x += av[k].x * bv.x - av[k].y * bv.y;
        acc[k].y += av[k].x * bv.y + av[k].y * bv.x;
      }
    }
    __syncthreads();
  }
  double* outp = vpart + (size_t)blockIdx.x * VH2;
  if (jcol < 129){
    #pragma unroll
    for (int k = 0; k < 5; ++k){
      int o0 = t0 + 16 * k;
      if (o0 < 65){
        int e = o0 * 129 + jcol;
        outp[2 * e] = acc[k].x;
        outp[2 * e + 1] = acc[k].y;
      }
    }
  }
}

// fk[o, c]: o in [0,33), c in [0,65) (freq c-32); grid (NCHUNK, 5)
__launch_bounds__(256)
__global__ void k_fk_main(const float* __restrict__ x, const float* __restrict__ y,
                          const float* __restrict__ wsf, double* __restrict__ fkpart){
  __shared__ double2 aL[16][48];
  __shared__ double2 bL[16][16];
  __shared__ float hxs[16][2];
  __shared__ float ys[16];
  const float hf = wsf[F_H];
  const int tid = threadIdx.x;
  const int t0 = tid >> 4, t1 = tid & 15;
  const int jcol = blockIdx.y * 16 + t1;   // 0..79 (valid < 65)
  double2 acc[3];
  #pragma unroll
  for (int k = 0; k < 3; ++k) acc[k] = make_double2(0.0, 0.0);
  const int p0 = blockIdx.x * PTSB2;
  const int pend = min(p0 + PTSB2, NTRAIN);
  for (int base = p0; base < pend; base += 16){
    if (tid < 32){
      int p = tid >> 1, d = tid & 1;
      int gp = base + p;
      hxs[p][d] = (gp < pend) ? __fmul_rn(hf, x[2 * gp + d]) : 0.f;
    } else if (tid < 48){
      int p = tid - 32;
      int gp = base + p;
      ys[p] = (gp < pend) ? y[gp] : 0.f;
    }
    __syncthreads();
    for (int i = tid; i < 16 * 48; i += 256){
      int p = i / 48, o = i - p * 48;
      int gp = base + p;
      double2 val = make_double2(0.0, 0.0);
      if (o < 33 && gp < pend){
        float t = __fmul_rn(hxs[p][0], (float)o);
        float sn, cs; sincosf(__fmul_rn(TPI32, t), &sn, &cs);
        val = make_double2((double)__fmul_rn(ys[p], cs), (double)__fmul_rn(ys[p], -sn));
      }
      aL[p][o] = val;
    }
    {
      int p = t0, c = t1;
      int gp = base + p;
      int j = blockIdx.y * 16 + c;
      double2 vb = make_double2(0.0, 0.0);
      if (gp < pend && j < 65){
        float t = __fmul_rn(hxs[p][1], (float)(j - 32));
        float sn, cs; sincosf(__fmul_rn(TPI32, t), &sn, &cs);
        vb = make_double2((double)cs, (double)(-sn));
      }
      bL[p][c] = vb;
    }
    __syncthreads();
    #pragma unroll 1
    for (int p = 0; p < 16; ++p){
      double2 bv = bL[p][t1];
      double2 av[3];
      #pragma unroll
      for (int k = 0; k < 3; ++k) av[k] = aL[p][t0 + 16 * k];
      #pragma unroll
      for (int k = 0; k < 3; ++k){
        acc[k].x += av[k].x * bv.x - av[k].y * bv.y;
        acc[k].y += av[k].x * bv.y + av[k].y * bv.x;
      }
    }
    __syncthreads();
  }
  double* outp = fkpart + (size_t)blockIdx.x * FH2;
  if (jcol < 65){
    #pragma unroll
    for (int k = 0; k < 3; ++k){
      int o0 = t0 + 16 * k;
      if (o0 < 33){
        int e = o0 * 65 + jcol;
        outp[2 * e] = acc[k].x;
        outp[2 * e + 1] = acc[k].y;
      }
    }
  }
}

__global__ void k_reduce_v(const double* __restrict__ wsd, float* __restrict__ wsf){
  int e = blockIdx.x * blockDim.x + threadIdx.x;
  if (e >= VHALF) return;
  const double* vp = wsd + D_VPART;
  double sr = 0.0, si = 0.0;
  for (int k = 0; k < NCHUNK; ++k){
    sr += vp[(size_t)k * VH2 + 2 * e];
    si += vp[(size_t)k * VH2 + 2 * e + 1];
  }
  float r32 = (float)sr, i32 = (float)si;
  int o0 = e / 129, j = e - o0 * 129;
  float2* vF = (float2*)(wsf + F_VF);
  vF[(o0 + 64) * 129 + j] = make_float2(r32, i32);
  if (o0 > 0) vF[(64 - o0) * 129 + (128 - j)] = make_float2(r32, -i32);
}

__global__ void k_reduce_fk(const double* __restrict__ wsd, float* __restrict__ wsf){
  int e = blockIdx.x * blockDim.x + threadIdx.x;
  if (e >= FKHALF) return;
  const double* fp = wsd + D_FKPART;
  double sr = 0.0, si = 0.0;
  for (int k = 0; k < NCHUNK; ++k){
    sr += fp[(size_t)k * FH2 + 2 * e];
    si += fp[(size_t)k * FH2 + 2 * e + 1];
  }
  float fr = (float)sr, fi = (float)si;
  int a = e / 65, c = e - a * 65;
  int ef = (a + 32) * 65 + c;
  float wf = wsf[F_WS + ef];
  float* rhs = wsf + F_RHS;
  rhs[2 * ef] = __fmul_rn(wf, fr);
  rhs[2 * ef + 1] = __fmul_rn(wf, fi);
  if (a > 0){
    int ef2 = (32 - a) * 65 + (64 - c);
    float wf2 = wsf[F_WS + ef2];
    rhs[2 * ef2] = __fmul_rn(wf2, fr);
    rhs[2 * ef2 + 1] = -__fmul_rn(wf2, fi);
  }
}

// fused vhat: block p computes T1 row p (f64) then vhat row p (c64)
__launch_bounds__(192)
__global__ void k_vhat(float* __restrict__ wsf){
  __shared__ double twc[129], tws[129];
  __shared__ double t1r[129], t1i[129];
  int p = blockIdx.x, t = threadIdx.x;
  if (t < 129){
    double ang = TWO_PI_D * (double)t / 129.0;
    double s, c; sincos(ang, &s, &c);
    twc[t] = c; tws[t] = s;
  }
  __syncthreads();
  if (t < 129){
    const float2* vF = (const float2*)(wsf + F_VF);
    int n = t;
    int nsrc = (n + 64) % 129;
    double ar = 0.0, ai = 0.0;
    for (int m = 0; m < 129; ++m){
      float2 v = vF[((m + 64) % 129) * 129 + nsrc];
      int idx = (p * m) % 129;
      double wr = twc[idx], wi = -tws[idx];
      ar += (double)v.x * wr - (double)v.y * wi;
      ai += (double)v.x * wi + (double)v.y * wr;
    }
    t1r[n] = ar; t1i[n] = ai;
  }
  __syncthreads();
  if (t < 129){
    int q = t;
    double ar = 0.0, ai = 0.0;
    for (int n = 0; n < 129; ++n){
      int idx = (q * n) % 129;
      double wr = twc[idx], wi = -tws[idx];
      ar += t1r[n] * wr - t1i[n] * wi;
      ai += t1r[n] * wi + t1i[n] * wr;
    }
    ((float2*)(wsf + F_VHAT))[p * 129 + q] = make_float2((float)ar, (float)ai);
  }
}

__global__ void k_cg_init(float* __restrict__ wsf){
  int e = blockIdx.x * blockDim.x + threadIdx.x;
  if (e >= M2) return;
  const float2* rhs = (const float2*)(wsf + F_RHS);
  float2 b = rhs[e];
  ((float2*)(wsf + F_X))[e] = make_float2(0.f, 0.f);
  ((float2*)(wsf + F_R))[e] = b;
  ((float2*)(wsf + F_P))[e] = b;
  wsf[F_PB + e] = __fadd_rn(__fmul_rn(b.x, b.x), __fmul_rn(b.y, b.y));
}

// ---- numpy pairwise sum (exact replication), n = 4225 ----
__device__ __forceinline__ float pw_leaf(const float* d, int o, int n){
  float r0 = d[o], r1 = d[o+1], r2 = d[o+2], r3 = d[o+3];
  float r4 = d[o+4], r5 = d[o+5], r6 = d[o+6], r7 = d[o+7];
  int i = 8;
  int lim = n - (n & 7);
  for (; i < lim; i += 8){
    r0 = __fadd_rn(r0, d[o+i]);   r1 = __fadd_rn(r1, d[o+i+1]);
    r2 = __fadd_rn(r2, d[o+i+2]); r3 = __fadd_rn(r3, d[o+i+3]);
    r4 = __fadd_rn(r4, d[o+i+4]); r5 = __fadd_rn(r5, d[o+i+5]);
    r6 = __fadd_rn(r6, d[o+i+6]); r7 = __fadd_rn(r7, d[o+i+7]);
  }
  float res = __fadd_rn(__fadd_rn(__fadd_rn(r0, r1), __fadd_rn(r2, r3)),
                        __fadd_rn(__fadd_rn(r4, r5), __fadd_rn(r6, r7)));
  for (; i < n; ++i) res = __fadd_rn(res, d[o+i]);
  return res;
}

__device__ __forceinline__ void pw_tree(const float* pb, float* T, int tid){
  if (tid < 16){
    const int tb[16] = {0,264,528,792,1056,1320,1584,1848,
                        2112,2376,2640,2904,3168,3432,3696,3960};
    int base = tb[tid];
    int sz3 = (tid == 15) ? 73 : 72;
    float L0 = pw_leaf(pb, base, 128);
    float L1 = pw_leaf(pb, base + 128, 64);
    float L2 = pw_leaf(pb, base + 192, sz3);
    T[tid] = __fadd_rn(L0, __fadd_rn(L1, L2));
  }
  __syncthreads();
  if (tid == 0){
    float s0 = __fadd_rn(__fadd_rn(T[0], T[1]), __fadd_rn(T[2], T[3]));
    float s1 = __fadd_rn(__fadd_rn(T[4], T[5]), __fadd_rn(T[6], T[7]));
    float s2 = __fadd_rn(__fadd_rn(T[8], T[9]), __fadd_rn(T[10], T[11]));
    float s3 = __fadd_rn(__fadd_rn(T[12], T[13]), __fadd_rn(T[14], T[15]));
    T[0] = __fadd_rn(__fadd_rn(s0, s1), __fadd_rn(s2, s3));
  }
}

__launch_bounds__(256)
__global__ void k_pair0(float* __restrict__ wsf){
  __shared__ float pb[M2];
  __shared__ float T[16];
  int tid = threadIdx.x;
  for (int i = tid; i < M2; i += 256) pb[i] = wsf[F_PB + i];
  __syncthreads();
  pw_tree(pb, T, tid);
  __syncthreads();
  if (tid == 0) wsf[F_RS] = T[0];
}

// fused W-fft + vhat multiply: block pr
__launch_bounds__(192)
__global__ void k_wfft(float* __restrict__ wsf){
  __shared__ double twc[129], tws[129];
  __shared__ double t1r[65], t1i[65];
  int pr = blockIdx.x, t = threadIdx.x;
  if (t < 129){
    double ang = TWO_PI_D * (double)t / 129.0;
    double s, c; sincos(ang, &s, &c);
    twc[t] = c; tws[t] = s;
  }
  __syncthreads();
  if (t < 65){
    const float2* P = (const float2*)(wsf + F_P);
    const float* W = wsf + F_WS;
    int n = t;
    double ar = 0.0, ai = 0.0;
    for (int m = 0; m < 65; ++m){
      int e = m * 65 + n;
      float2 p = P[e];
      float w = W[e];
      float wbr = __fmul_rn(w, p.x), wbi = __fmul_rn(w, p.y);
      int idx = (pr * m) % 129;
      double wr = twc[idx], wi = -tws[idx];
      ar += (double)wbr * wr - (double)wbi * wi;
      ai += (double)wbr * wi + (double)wbi * wr;
    }
    t1r[n] = ar; t1i[n] = ai;
  }
  __syncthreads();
  if (t < 129){
    int q = t;
    double ar = 0.0, ai = 0.0;
    for (int n = 0; n < 65; ++n){
      int idx = (q * n) % 129;
      double wr = twc[idx], wi = -tws[idx];
      ar += t1r[n] * wr - t1i[n] * wi;
      ai += t1r[n] * wi + t1i[n] * wr;
    }
    float Wr = (float)ar, Wi = (float)ai;   // c64 cast of fftn output
    float2 v = ((const float2*)(wsf + F_VHAT))[pr * 129 + q];
    float prre = __fsub_rn(__fmul_rn(v.x, Wr), __fmul_rn(v.y, Wi));
    float prim = __fadd_rn(__fmul_rn(v.x, Wi), __fmul_rn(v.y, Wr));
    ((float2*)(wsf + F_PROD))[pr * 129 + q] = make_float2(prre, prim);
  }
}

// fused ifft + Ap + pb: block m
__launch_bounds__(192)
__global__ void k_ifft(float* __restrict__ wsf){
  __shared__ double twc[129], tws[129];
  __shared__ double ur[129], ui[129];
  int m = blockIdx.x, t = threadIdx.x;
  if (t < 129){
    double ang = TWO_PI_D * (double)t / 129.0;
    double s, c; sincos(ang, &s, &c);
    twc[t] = c; tws[t] = s;
  }
  __syncthreads();
  if (t < 129){
    const float2* prod = (const float2*)(wsf + F_PROD);
    int q = t;
    double ar = 0.0, ai = 0.0;
    for (int pr = 0; pr < 129; ++pr){
      float2 v = prod[pr * 129 + q];
      int idx = (m * pr) % 129;
      double wr = twc[idx], wi = tws[idx];   // e^{+i}
      ar += (double)v.x * wr - (double)v.y * wi;
      ai += (double)v.x * wi + (double)v.y * wr;
    }
    const double sc = 1.0 / 129.0;
    ur[q] = ar * sc; ui[q] = ai * sc;
  }
  __syncthreads();
  if (t < 65){
    int n = t;
    double ar = 0.0, ai = 0.0;
    for (int q = 0; q < 129; ++q){
      int idx = (n * q) % 129;
      double wr = twc[idx], wi = tws[idx];   // e^{+i}
      ar += ur[q] * wr - ui[q] * wi;
      ai += ur[q] * wi + ui[q] * wr;
    }
    const double sc = 1.0 / 129.0;
    float Twr = (float)(ar * sc), Twi = (float)(ai * sc);  // c64 cast
    int e = m * 65 + n;
    float w = wsf[F_WS + e];
    float2 p = ((const float2*)(wsf + F_P))[e];
    float Apx = __fadd_rn(__fmul_rn(w, Twr), __fmul_rn(0.05f, p.x));
    float Apy = __fadd_rn(__fmul_rn(w, Twi), __fmul_rn(0.05f, p.y));
    ((float2*)(wsf + F_AP))[e] = make_float2(Apx, Apy);
    wsf[F_PB + e] = __fadd_rn(__fmul_rn(p.x, Apx), __fmul_rn(p.y, Apy));
  }
}

// fused scalar step: pAp pairwise -> alpha -> x,r update -> rsn pairwise -> beta -> p update
__launch_bounds__(256)
__global__ void k_cgstep(float* __restrict__ wsf){
  __shared__ float pb[M2];
  __shared__ float T[16];
  __shared__ float sh[2];
  int tid = threadIdx.x;
  for (int i = tid; i < M2; i += 256) pb[i] = wsf[F_PB + i];
  __syncthreads();
  pw_tree(pb, T, tid);      // pAp
  __syncthreads();
  if (tid == 0){
    float rs = wsf[F_RS];
    sh[1] = rs;
    sh[0] = __fdiv_rn(rs, T[0]);   // alpha
  }
  __syncthreads();
  float alpha = sh[0];
  float2* X = (float2*)(wsf + F_X);
  float2* R = (float2*)(wsf + F_R);
  float2* P = (float2*)(wsf + F_P);
  const float2* AP = (const float2*)(wsf + F_AP);
  for (int e = tid; e < M2; e += 256){
    float2 p = P[e], ap = AP[e], xv = X[e], rv = R[e];
    xv.x = __fadd_rn(xv.x, __fmul_rn(alpha, p.x));
    xv.y = __fadd_rn(xv.y, __fmul_rn(alpha, p.y));
    rv.x = __fsub_rn(rv.x, __fmul_rn(alpha, ap.x));
    rv.y = __fsub_rn(rv.y, __fmul_rn(alpha, ap.y));
    X[e] = xv; R[e] = rv;
    pb[e] = __fadd_rn(__fmul_rn(rv.x, rv.x), __fmul_rn(rv.y, rv.y));
  }
  __syncthreads();
  pw_tree(pb, T, tid);      // rsn
  __syncthreads();
  if (tid == 0){
    float rsn = T[0];
    sh[0] = __fdiv_rn(rsn, sh[1]);  // beta
    wsf[F_RS] = rsn;
  }
  __syncthreads();
  float beta = sh[0];
  for (int e = tid; e < M2; e += 256){
    float2 rv = R[e], p = P[e];
    P[e] = make_float2(__fadd_rn(rv.x, __fmul_rn(beta, p.x)),
                       __fadd_rn(rv.y, __fmul_rn(beta, p.y)));
  }
}

__launch_bounds__(256)
__global__ void k_predict(const float* __restrict__ xn, const float* __restrict__ wsf,
                          float* __restrict__ out){
  __shared__ double fbRe[M2];
  __shared__ double fbIm[M2];
  const float hf = wsf[F_H];
  const float* wsq = wsf + F_WS;
  const float2* xb = (const float2*)(wsf + F_X);
  int tid = threadIdx.x;
  for (int i = tid; i < M2; i += 256){
    float w = wsq[i]; float2 q = xb[i];
    fbRe[i] = (double)__fmul_rn(w, q.x);
    fbIm[i] = (double)__fmul_rn(w, q.y);
  }
  __syncthreads();
  int lane = tid & 63;
  int wid = (blockIdx.x * 256 + tid) >> 6;
  int nw = (gridDim.x * 256) >> 6;
  for (int n = wid; n < NTEST; n += nw){
    float hx0 = __fmul_rn(hf, xn[2 * n]);
    float hx1 = __fmul_rn(hf, xn[2 * n + 1]);
    float t0 = __fmul_rn(hx0, (float)(lane - 32));
    float s0, c0; sincosf(__fmul_rn(TPI32, t0), &s0, &c0);
    float t1 = __fmul_rn(hx1, (float)(lane - 32));
    float s1, c1; sincosf(__fmul_rn(TPI32, t1), &s1, &c1);
    float t0x = __fmul_rn(hx0, 32.0f);
    float s0x, c0x; sincosf(__fmul_rn(TPI32, t0x), &s0x, &c0x);
    float t1x = __fmul_rn(hx1, 32.0f);
    float s1x, c1x; sincosf(__fmul_rn(TPI32, t1x), &s1x, &c1x);
    double e0r = (double)c0, e0i = (double)s0;
    double e1r = (double)c1, e1i = (double)s1;
    double gr = 0.0, gi = 0.0;
    for (int a = 0; a < 64; ++a){
      double er = __shfl(e0r, a, 64);
      double ei = __shfl(e0i, a, 64);
      double fr = fbRe[a * 65 + lane];
      double fi = fbIm[a * 65 + lane];
      gr += fr * er - fi * ei;
      gi += fr * ei + fi * er;
    }
    {
      double fr = fbRe[64 * 65 + lane], fi = fbIm[64 * 65 + lane];
      gr += fr * (double)c0x - fi * (double)s0x;
      gi += fr * (double)s0x + fi * (double)c0x;
    }
    double contrib = gr * e1r - gi * e1i;
    {
      double fr = fbRe[lane * 65 + 64], fi = fbIm[lane * 65 + 64];
      double ur = fr * e0r - fi * e0i;
      double ui = fr * e0i + fi * e0r;
      contrib += ur * (double)c1x - ui * (double)s1x;
      if (lane == 0){
        double fr2 = fbRe[64 * 65 + 64], fi2 = fbIm[64 * 65 + 64];
        double vr = fr2 * (double)c0x - fi2 * (double)s0x;
        double vi = fr2 * (double)s0x + fi2 * (double)c0x;
        contrib += vr * (double)c1x - vi * (double)s1x;
      }
    }
    for (int off = 32; off; off >>= 1) contrib += __shfl_xor(contrib, off, 64);
    if (lane == 0) out[n] = (float)contrib;
  }
}

extern "C" void kernel_launch(void* const* d_in, const int* in_sizes, int n_in,
                              void* d_out, int out_size, void* d_ws, size_t ws_size,
                              hipStream_t stream){
  const float* x = (const float*)d_in[0];
  const float* y = (const float*)d_in[1];
  const float* xnew = (const float*)d_in[2];
  float* wsf = (float*)d_ws;
  double* wsd = (double*)d_ws;
  float* out = (float*)d_out;
  unsigned* mm = (unsigned*)(wsf + 4);

  k_init<<<1, 64, 0, stream>>>(mm);
  k_minmax<<<256, 256, 0, stream>>>(x, xnew, mm);
  k_setup<<<1, 256, 0, stream>>>(wsf);
  k_v_main<<<dim3(NCHUNK, 9), 256, 0, stream>>>(x, wsf, wsd + D_VPART);
  k_fk_main<<<dim3(NCHUNK, 5), 256, 0, stream>>>(x, y, wsf, wsd + D_FKPART);
  k_reduce_v<<<33, 256, 0, stream>>>(wsd, wsf);
  k_reduce_fk<<<9, 256, 0, stream>>>(wsd, wsf);
  k_vhat<<<129, 192, 0, stream>>>(wsf);
  k_cg_init<<<17, 256, 0, stream>>>(wsf);
  k_pair0<<<1, 256, 0, stream>>>(wsf);
  for (int it = 0; it < CGITERS; ++it){
    k_wfft<<<129, 192, 0, stream>>>(wsf);
    k_ifft<<<65, 192, 0, stream>>>(wsf);
    k_cgstep<<<1, 256, 0, stream>>>(wsf);
  }
  k_predict<<<256, 256, 0, stream>>>(xnew, wsf, out);
}

// Round 19
// 2172.963 us; speedup vs baseline: 1.4371x; 1.0506x over previous
//
#include <hip/hip_runtime.h>
#include <math.h>

#define M2 4225
#define NTRAIN 100000
#define NTEST 50000
#define CGITERS 30
#define TWO_PI_D 6.283185307179586476925287
#define TPI32 6.28318530717958647692f

// ---- float offsets ----
#define F_H 0
#define F_RS 1
#define F_PAP 2
#define F_RSN 3
// mm encoded uints at floats 4..7
#define F_WS 8          // 4225
#define F_RHS 4234      // 8450 (float2)
#define F_X 12684
#define F_R 21134
#define F_P 29584
#define F_AP 38034
#define F_PB 46484      // 4225 products
#define F_VF 50710      // 129*129 float2 = 33282
#define F_VHAT 83992    // 33282
#define F_PROD 117274   // 33282 (end 150556)
// ---- double offsets ----
#define D_VPART 125330  // 128*16770
#define D_FKPART 2271890 // 128*4290 (end 2821010 dbl = 22.6MB)

#define NCHUNK 128
#define PTSB2 782
#define VHALF 8385
#define VH2 16770
#define FKHALF 2145
#define FH2 4290

__device__ __forceinline__ unsigned fkey(float f){
  unsigned u = __float_as_uint(f);
  return (u & 0x80000000u) ? ~u : (u | 0x80000000u);
}
__device__ __forceinline__ float fdec(unsigned k){
  unsigned u = (k & 0x80000000u) ? (k & 0x7fffffffu) : ~k;
  return __uint_as_float(u);
}

__global__ void k_init(unsigned* mm){
  if (threadIdx.x == 0){
    mm[0] = 0xFFFFFFFFu; mm[1] = 0u; mm[2] = 0xFFFFFFFFu; mm[3] = 0u;
  }
}

__global__ void k_minmax(const float* __restrict__ x, const float* __restrict__ xn,
                         unsigned* __restrict__ mm){
  int tid = blockIdx.x * blockDim.x + threadIdx.x;
  int str = gridDim.x * blockDim.x;
  float mn0 = 1e30f, mx0 = -1e30f, mn1 = 1e30f, mx1 = -1e30f;
  const float2* a = (const float2*)x;
  for (int i = tid; i < NTRAIN; i += str){
    float2 v = a[i];
    mn0 = fminf(mn0, v.x); mx0 = fmaxf(mx0, v.x);
    mn1 = fminf(mn1, v.y); mx1 = fmaxf(mx1, v.y);
  }
  const float2* b = (const float2*)xn;
  for (int i = tid; i < NTEST; i += str){
    float2 v = b[i];
    mn0 = fminf(mn0, v.x); mx0 = fmaxf(mx0, v.x);
    mn1 = fminf(mn1, v.y); mx1 = fmaxf(mx1, v.y);
  }
  for (int off = 32; off; off >>= 1){
    mn0 = fminf(mn0, __shfl_xor(mn0, off, 64));
    mx0 = fmaxf(mx0, __shfl_xor(mx0, off, 64));
    mn1 = fminf(mn1, __shfl_xor(mn1, off, 64));
    mx1 = fmaxf(mx1, __shfl_xor(mx1, off, 64));
  }
  if ((threadIdx.x & 63) == 0){
    atomicMin(&mm[0], fkey(mn0)); atomicMax(&mm[1], fkey(mx0));
    atomicMin(&mm[2], fkey(mn1)); atomicMax(&mm[3], fkey(mx1));
  }
}

__global__ void k_setup(float* __restrict__ wsf){
  const unsigned* mm = (const unsigned*)(wsf + 4);
  float mn0 = fdec(mm[0]), mx0 = fdec(mm[1]);
  float mn1 = fdec(mm[2]), mx1 = fdec(mm[3]);
  float d0 = __fsub_rn(mx0, mn0), d1 = __fsub_rn(mx1, mn1);
  float L = fmaxf(d0, d1);
  if (L <= 1e-9f) L = 1.0f;
  float hf = __fdiv_rn(1.0f, L);
  if (threadIdx.x == 0) wsf[F_H] = hf;
  const float c0f = (float)(TWO_PI_D * 0.01);
  const float c1f = (float)(-2.0 * 9.869604401089358618834 * 0.01);
  float h2f = __fmul_rn(hf, hf);
  for (int e = threadIdx.x; e < M2; e += blockDim.x){
    int r = e / 65, c = e - r * 65;
    float xi0 = __fmul_rn(hf, (float)(r - 32));
    float xi1 = __fmul_rn(hf, (float)(c - 32));
    float sq = __fadd_rn(__fmul_rn(xi0, xi0), __fmul_rn(xi1, xi1));
    float spec = __fmul_rn(c0f, expf(__fmul_rn(c1f, sq)));
    wsf[F_WS + e] = sqrtf(__fmul_rn(spec, h2f));
  }
}

// Fused quadrature GEMMs. grid (NCHUNK, 8):
//   y in [0,5): v tile  (32 cols of 129, col offset j-64), acc[5][2]
//   y in [5,8): fk tile (32 cols of 65,  col offset j-32), acc[3][2]
// Per-entry accumulation order over points is identical to the passing R18
// kernels (thread-serial over p); only cross-entry interleave changes.
__launch_bounds__(256)
__global__ void k_vfk(const float* __restrict__ x, const float* __restrict__ y,
                      const float* __restrict__ wsf,
                      double* __restrict__ vpart, double* __restrict__ fkpart){
  __shared__ double2 aL[16][80];
  __shared__ double2 bL[16][32];
  __shared__ float hxs[16][2];
  __shared__ float ys[16];
  const float hf = wsf[F_H];
  const int tid = threadIdx.x;
  const int t0 = tid >> 4, t1 = tid & 15;
  const bool isV = (blockIdx.y < 5);
  const int colbase = (isV ? blockIdx.y : (blockIdx.y - 5)) * 32;
  const int p0 = blockIdx.x * PTSB2;
  const int pend = min(p0 + PTSB2, NTRAIN);

  if (isV){
    double2 acc[5][2];
    #pragma unroll
    for (int k = 0; k < 5; ++k){ acc[k][0] = make_double2(0.0, 0.0); acc[k][1] = make_double2(0.0, 0.0); }
    for (int base = p0; base < pend; base += 16){
      if (tid < 32){
        int p = tid >> 1, d = tid & 1;
        int gp = base + p;
        hxs[p][d] = (gp < pend) ? __fmul_rn(hf, x[2 * gp + d]) : 0.f;
      }
      __syncthreads();
      for (int i = tid; i < 16 * 80; i += 256){
        int p = i / 80;
        int o = i - p * 80;
        int gp = base + p;
        double2 va = make_double2(0.0, 0.0);
        if (gp < pend && o < 65){
          float t = __fmul_rn(hxs[p][0], (float)o);
          float sn, cs; sincosf(__fmul_rn(TPI32, t), &sn, &cs);
          va = make_double2((double)cs, (double)(-sn));
        }
        aL[p][o] = va;
      }
      for (int i = tid; i < 16 * 32; i += 256){
        int p = i >> 5, c = i & 31;
        int gp = base + p;
        int j = colbase + c;
        double2 vb = make_double2(0.0, 0.0);
        if (gp < pend && j < 129){
          float t = __fmul_rn(hxs[p][1], (float)(j - 64));
          float sn, cs; sincosf(__fmul_rn(TPI32, t), &sn, &cs);
          vb = make_double2((double)cs, (double)(-sn));
        }
        bL[p][c] = vb;
      }
      __syncthreads();
      #pragma unroll 1
      for (int p = 0; p < 16; ++p){
        double2 bv0 = bL[p][t1];
        double2 bv1 = bL[p][t1 + 16];
        double2 av[5];
        #pragma unroll
        for (int k = 0; k < 5; ++k) av[k] = aL[p][t0 + 16 * k];
        #pragma unroll
        for (int k = 0; k < 5; ++k){
          acc[k][0].x += av[k].x * bv0.x - av[k].y * bv0.y;
          acc[k][0].y += av[k].x * bv0.y + av[k].y * bv0.x;
          acc[k][1].x += av[k].x * bv1.x - av[k].y * bv1.y;
          acc[k][1].y += av[k].x * bv1.y + av[k].y * bv1.x;
        }
      }
      __syncthreads();
    }
    double* outp = vpart + (size_t)blockIdx.x * VH2;
    #pragma unroll
    for (int k = 0; k < 5; ++k){
      int o0 = t0 + 16 * k;
      if (o0 < 65){
        #pragma unroll
        for (int cc = 0; cc < 2; ++cc){
          int jcol = colbase + t1 + 16 * cc;
          if (jcol < 129){
            int e = o0 * 129 + jcol;
            outp[2 * e] = acc[k][cc].x;
            outp[2 * e + 1] = acc[k][cc].y;
          }
        }
      }
    }
  } else {
    double2 acc[3][2];
    #pragma unroll
    for (int k = 0; k < 3; ++k){ acc[k][0] = make_double2(0.0, 0.0); acc[k][1] = make_double2(0.0, 0.0); }
    for (int base = p0; base < pend; base += 16){
      if (tid < 32){
        int p = tid >> 1, d = tid & 1;
        int gp = base + p;
        hxs[p][d] = (gp < pend) ? __fmul_rn(hf, x[2 * gp + d]) : 0.f;
      } else if (tid < 48){
        int p = tid - 32;
        int gp = base + p;
        ys[p] = (gp < pend) ? y[gp] : 0.f;
      }
      __syncthreads();
      for (int i = tid; i < 16 * 48; i += 256){
        int p = i / 48, o = i - p * 48;
        int gp = base + p;
        double2 val = make_double2(0.0, 0.0);
        if (o < 33 && gp < pend){
          float t = __fmul_rn(hxs[p][0], (float)o);
          float sn, cs; sincosf(__fmul_rn(TPI32, t), &sn, &cs);
          val = make_double2((double)__fmul_rn(ys[p], cs), (double)__fmul_rn(ys[p], -sn));
        }
        aL[p][o] = val;
      }
      for (int i = tid; i < 16 * 32; i += 256){
        int p = i >> 5, c = i & 31;
        int gp = base + p;
        int j = colbase + c;
        double2 vb = make_double2(0.0, 0.0);
        if (gp < pend && j < 65){
          float t = __fmul_rn(hxs[p][1], (float)(j - 32));
          float sn, cs; sincosf(__fmul_rn(TPI32, t), &sn, &cs);
          vb = make_double2((double)cs, (double)(-sn));
        }
        bL[p][c] = vb;
      }
      __syncthreads();
      #pragma unroll 1
      for (int p = 0; p < 16; ++p){
        double2 bv0 = bL[p][t1];
        double2 bv1 = bL[p][t1 + 16];
        double2 av[3];
        #pragma unroll
        for (int k = 0; k < 3; ++k) av[k] = aL[p][t0 + 16 * k];
        #pragma unroll
        for (int k = 0; k < 3; ++k){
          acc[k][0].x += av[k].x * bv0.x - av[k].y * bv0.y;
          acc[k][0].y += av[k].x * bv0.y + av[k].y * bv0.x;
          acc[k][1].x += av[k].x * bv1.x - av[k].y * bv1.y;
          acc[k][1].y += av[k].x * bv1.y + av[k].y * bv1.x;
        }
      }
      __syncthreads();
    }
    double* outp = fkpart + (size_t)blockIdx.x * FH2;
    #pragma unroll
    for (int k = 0; k < 3; ++k){
      int o0 = t0 + 16 * k;
      if (o0 < 33){
        #pragma unroll
        for (int cc = 0; cc < 2; ++cc){
          int jcol = colbase + t1 + 16 * cc;
          if (jcol < 65){
            int e = o0 * 65 + jcol;
            outp[2 * e] = acc[k][cc].x;
            outp[2 * e + 1] = acc[k][cc].y;
          }
        }
      }
    }
  }
}

__global__ void k_reduce_v(const double* __restrict__ wsd, float* __restrict__ wsf){
  int e = blockIdx.x * blockDim.x + threadIdx.x;
  if (e >= VHALF) return;
  const double* vp = wsd + D_VPART;
  double sr = 0.0, si = 0.0;
  for (int k = 0; k < NCHUNK; ++k){
    sr += vp[(size_t)k * VH2 + 2 * e];
    si += vp[(size_t)k * VH2 + 2 * e + 1];
  }
  float r32 = (float)sr, i32 = (float)si;
  int o0 = e / 129, j = e - o0 * 129;
  float2* vF = (float2*)(wsf + F_VF);
  vF[(o0 + 64) * 129 + j] = make_float2(r32, i32);
  if (o0 > 0) vF[(64 - o0) * 129 + (128 - j)] = make_float2(r32, -i32);
}

__global__ void k_reduce_fk(const double* __restrict__ wsd, float* __restrict__ wsf){
  int e = blockIdx.x * blockDim.x + threadIdx.x;
  if (e >= FKHALF) return;
  const double* fp = wsd + D_FKPART;
  double sr = 0.0, si = 0.0;
  for (int k = 0; k < NCHUNK; ++k){
    sr += fp[(size_t)k * FH2 + 2 * e];
    si += fp[(size_t)k * FH2 + 2 * e + 1];
  }
  float fr = (float)sr, fi = (float)si;
  int a = e / 65, c = e - a * 65;
  int ef = (a + 32) * 65 + c;
  float wf = wsf[F_WS + ef];
  float* rhs = wsf + F_RHS;
  rhs[2 * ef] = __fmul_rn(wf, fr);
  rhs[2 * ef + 1] = __fmul_rn(wf, fi);
  if (a > 0){
    int ef2 = (32 - a) * 65 + (64 - c);
    float wf2 = wsf[F_WS + ef2];
    rhs[2 * ef2] = __fmul_rn(wf2, fr);
    rhs[2 * ef2 + 1] = -__fmul_rn(wf2, fi);
  }
}

// fused vhat: block p computes T1 row p (f64) then vhat row p (c64)
__launch_bounds__(192)
__global__ void k_vhat(float* __restrict__ wsf){
  __shared__ double twc[129], tws[129];
  __shared__ double t1r[129], t1i[129];
  int p = blockIdx.x, t = threadIdx.x;
  if (t < 129){
    double ang = TWO_PI_D * (double)t / 129.0;
    double s, c; sincos(ang, &s, &c);
    twc[t] = c; tws[t] = s;
  }
  __syncthreads();
  if (t < 129){
    const float2* vF = (const float2*)(wsf + F_VF);
    int n = t;
    int nsrc = (n + 64) % 129;
    double ar = 0.0, ai = 0.0;
    for (int m = 0; m < 129; ++m){
      float2 v = vF[((m + 64) % 129) * 129 + nsrc];
      int idx = (p * m) % 129;
      double wr = twc[idx], wi = -tws[idx];
      ar += (double)v.x * wr - (double)v.y * wi;
      ai += (double)v.x * wi + (double)v.y * wr;
    }
    t1r[n] = ar; t1i[n] = ai;
  }
  __syncthreads();
  if (t < 129){
    int q = t;
    double ar = 0.0, ai = 0.0;
    for (int n = 0; n < 129; ++n){
      int idx = (q * n) % 129;
      double wr = twc[idx], wi = -tws[idx];
      ar += t1r[n] * wr - t1i[n] * wi;
      ai += t1r[n] * wi + t1i[n] * wr;
    }
    ((float2*)(wsf + F_VHAT))[p * 129 + q] = make_float2((float)ar, (float)ai);
  }
}

__global__ void k_cg_init(float* __restrict__ wsf){
  int e = blockIdx.x * blockDim.x + threadIdx.x;
  if (e >= M2) return;
  const float2* rhs = (const float2*)(wsf + F_RHS);
  float2 b = rhs[e];
  ((float2*)(wsf + F_X))[e] = make_float2(0.f, 0.f);
  ((float2*)(wsf + F_R))[e] = b;
  ((float2*)(wsf + F_P))[e] = b;
  wsf[F_PB + e] = __fadd_rn(__fmul_rn(b.x, b.x), __fmul_rn(b.y, b.y));
}

// ---- numpy pairwise sum (exact replication), n = 4225 ----
__device__ __forceinline__ float pw_leaf(const float* d, int o, int n){
  float r0 = d[o], r1 = d[o+1], r2 = d[o+2], r3 = d[o+3];
  float r4 = d[o+4], r5 = d[o+5], r6 = d[o+6], r7 = d[o+7];
  int i = 8;
  int lim = n - (n & 7);
  for (; i < lim; i += 8){
    r0 = __fadd_rn(r0, d[o+i]);   r1 = __fadd_rn(r1, d[o+i+1]);
    r2 = __fadd_rn(r2, d[o+i+2]); r3 = __fadd_rn(r3, d[o+i+3]);
    r4 = __fadd_rn(r4, d[o+i+4]); r5 = __fadd_rn(r5, d[o+i+5]);
    r6 = __fadd_rn(r6, d[o+i+6]); r7 = __fadd_rn(r7, d[o+i+7]);
  }
  float res = __fadd_rn(__fadd_rn(__fadd_rn(r0, r1), __fadd_rn(r2, r3)),
                        __fadd_rn(__fadd_rn(r4, r5), __fadd_rn(r6, r7)));
  for (; i < n; ++i) res = __fadd_rn(res, d[o+i]);
  return res;
}

__device__ __forceinline__ void pw_tree(const float* pb, float* T, int tid){
  if (tid < 16){
    const int tb[16] = {0,264,528,792,1056,1320,1584,1848,
                        2112,2376,2640,2904,3168,3432,3696,3960};
    int base = tb[tid];
    int sz3 = (tid == 15) ? 73 : 72;
    float L0 = pw_leaf(pb, base, 128);
    float L1 = pw_leaf(pb, base + 128, 64);
    float L2 = pw_leaf(pb, base + 192, sz3);
    T[tid] = __fadd_rn(L0, __fadd_rn(L1, L2));
  }
  __syncthreads();
  if (tid == 0){
    float s0 = __fadd_rn(__fadd_rn(T[0], T[1]), __fadd_rn(T[2], T[3]));
    float s1 = __fadd_rn(__fadd_rn(T[4], T[5]), __fadd_rn(T[6], T[7]));
    float s2 = __fadd_rn(__fadd_rn(T[8], T[9]), __fadd_rn(T[10], T[11]));
    float s3 = __fadd_rn(__fadd_rn(T[12], T[13]), __fadd_rn(T[14], T[15]));
    T[0] = __fadd_rn(__fadd_rn(s0, s1), __fadd_rn(s2, s3));
  }
}

__launch_bounds__(256)
__global__ void k_pair0(float* __restrict__ wsf){
  __shared__ float pb[M2];
  __shared__ float T[16];
  int tid = threadIdx.x;
  for (int i = tid; i < M2; i += 256) pb[i] = wsf[F_PB + i];
  __syncthreads();
  pw_tree(pb, T, tid);
  __syncthreads();
  if (tid == 0) wsf[F_RS] = T[0];
}

// fused W-fft + vhat multiply: block pr
__launch_bounds__(192)
__global__ void k_wfft(float* __restrict__ wsf){
  __shared__ double twc[129], tws[129];
  __shared__ double t1r[65], t1i[65];
  int pr = blockIdx.x, t = threadIdx.x;
  if (t < 129){
    double ang = TWO_PI_D * (double)t / 129.0;
    double s, c; sincos(ang, &s, &c);
    twc[t] = c; tws[t] = s;
  }
  __syncthreads();
  if (t < 65){
    const float2* P = (const float2*)(wsf + F_P);
    const float* W = wsf + F_WS;
    int n = t;
    double ar = 0.0, ai = 0.0;
    for (int m = 0; m < 65; ++m){
      int e = m * 65 + n;
      float2 p = P[e];
      float w = W[e];
      float wbr = __fmul_rn(w, p.x), wbi = __fmul_rn(w, p.y);
      int idx = (pr * m) % 129;
      double wr = twc[idx], wi = -tws[idx];
      ar += (double)wbr * wr - (double)wbi * wi;
      ai += (double)wbr * wi + (double)wbi * wr;
    }
    t1r[n] = ar; t1i[n] = ai;
  }
  __syncthreads();
  if (t < 129){
    int q = t;
    double ar = 0.0, ai = 0.0;
    for (int n = 0; n < 65; ++n){
      int idx = (q * n) % 129;
      double wr = twc[idx], wi = -tws[idx];
      ar += t1r[n] * wr - t1i[n] * wi;
      ai += t1r[n] * wi + t1i[n] * wr;
    }
    float Wr = (float)ar, Wi = (float)ai;   // c64 cast of fftn output
    float2 v = ((const float2*)(wsf + F_VHAT))[pr * 129 + q];
    float prre = __fsub_rn(__fmul_rn(v.x, Wr), __fmul_rn(v.y, Wi));
    float prim = __fadd_rn(__fmul_rn(v.x, Wi), __fmul_rn(v.y, Wr));
    ((float2*)(wsf + F_PROD))[pr * 129 + q] = make_float2(prre, prim);
  }
}

// fused ifft + Ap + pb: block m
__launch_bounds__(192)
__global__ void k_ifft(float* __restrict__ wsf){
  __shared__ double twc[129], tws[129];
  __shared__ double ur[129], ui[129];
  int m = blockIdx.x, t = threadIdx.x;
  if (t < 129){
    double ang = TWO_PI_D * (double)t / 129.0;
    double s, c; sincos(ang, &s, &c);
    twc[t] = c; tws[t] = s;
  }
  __syncthreads();
  if (t < 129){
    const float2* prod = (const float2*)(wsf + F_PROD);
    int q = t;
    double ar = 0.0, ai = 0.0;
    for (int pr = 0; pr < 129; ++pr){
      float2 v = prod[pr * 129 + q];
      int idx = (m * pr) % 129;
      double wr = twc[idx], wi = tws[idx];   // e^{+i}
      ar += (double)v.x * wr - (double)v.y * wi;
      ai += (double)v.x * wi + (double)v.y * wr;
    }
    const double sc = 1.0 / 129.0;
    ur[q] = ar * sc; ui[q] = ai * sc;
  }
  __syncthreads();
  if (t < 65){
    int n = t;
    double ar = 0.0, ai = 0.0;
    for (int q = 0; q < 129; ++q){
      int idx = (n * q) % 129;
      double wr = twc[idx], wi = tws[idx];   // e^{+i}
      ar += ur[q] * wr - ui[q] * wi;
      ai += ur[q] * wi + ui[q] * wr;
    }
    const double sc = 1.0 / 129.0;
    float Twr = (float)(ar * sc), Twi = (float)(ai * sc);  // c64 cast
    int e = m * 65 + n;
    float w = wsf[F_WS + e];
    float2 p = ((const float2*)(wsf + F_P))[e];
    float Apx = __fadd_rn(__fmul_rn(w, Twr), __fmul_rn(0.05f, p.x));
    float Apy = __fadd_rn(__fmul_rn(w, Twi), __fmul_rn(0.05f, p.y));
    ((float2*)(wsf + F_AP))[e] = make_float2(Apx, Apy);
    wsf[F_PB + e] = __fadd_rn(__fmul_rn(p.x, Apx), __fmul_rn(p.y, Apy));
  }
}

// fused scalar step: pAp pairwise -> alpha -> x,r update -> rsn pairwise -> beta -> p update
__launch_bounds__(256)
__global__ void k_cgstep(float* __restrict__ wsf){
  __shared__ float pb[M2];
  __shared__ float T[16];
  __shared__ float sh[2];
  int tid = threadIdx.x;
  for (int i = tid; i < M2; i += 256) pb[i] = wsf[F_PB + i];
  __syncthreads();
  pw_tree(pb, T, tid);      // pAp
  __syncthreads();
  if (tid == 0){
    float rs = wsf[F_RS];
    sh[1] = rs;
    sh[0] = __fdiv_rn(rs, T[0]);   // alpha
  }
  __syncthreads();
  float alpha = sh[0];
  float2* X = (float2*)(wsf + F_X);
  float2* R = (float2*)(wsf + F_R);
  float2* P = (float2*)(wsf + F_P);
  const float2* AP = (const float2*)(wsf + F_AP);
  for (int e = tid; e < M2; e += 256){
    float2 p = P[e], ap = AP[e], xv = X[e], rv = R[e];
    xv.x = __fadd_rn(xv.x, __fmul_rn(alpha, p.x));
    xv.y = __fadd_rn(xv.y, __fmul_rn(alpha, p.y));
    rv.x = __fsub_rn(rv.x, __fmul_rn(alpha, ap.x));
    rv.y = __fsub_rn(rv.y, __fmul_rn(alpha, ap.y));
    X[e] = xv; R[e] = rv;
    pb[e] = __fadd_rn(__fmul_rn(rv.x, rv.x), __fmul_rn(rv.y, rv.y));
  }
  __syncthreads();
  pw_tree(pb, T, tid);      // rsn
  __syncthreads();
  if (tid == 0){
    float rsn = T[0];
    sh[0] = __fdiv_rn(rsn, sh[1]);  // beta
    wsf[F_RS] = rsn;
  }
  __syncthreads();
  float beta = sh[0];
  for (int e = tid; e < M2; e += 256){
    float2 rv = R[e], p = P[e];
    P[e] = make_float2(__fadd_rn(rv.x, __fmul_rn(beta, p.x)),
                       __fadd_rn(rv.y, __fmul_rn(beta, p.y)));
  }
}

__launch_bounds__(256)
__global__ void k_predict(const float* __restrict__ xn, const float* __restrict__ wsf,
                          float* __restrict__ out){
  __shared__ double fbRe[M2];
  __shared__ double fbIm[M2];
  const float hf = wsf[F_H];
  const float* wsq = wsf + F_WS;
  const float2* xb = (const float2*)(wsf + F_X);
  int tid = threadIdx.x;
  for (int i = tid; i < M2; i += 256){
    float w = wsq[i]; float2 q = xb[i];
    fbRe[i] = (double)__fmul_rn(w, q.x);
    fbIm[i] = (double)__fmul_rn(w, q.y);
  }
  __syncthreads();
  int lane = tid & 63;
  int wid = (blockIdx.x * 256 + tid) >> 6;
  int nw = (gridDim.x * 256) >> 6;
  for (int n = wid; n < NTEST; n += nw){
    float hx0 = __fmul_rn(hf, xn[2 * n]);
    float hx1 = __fmul_rn(hf, xn[2 * n + 1]);
    float t0 = __fmul_rn(hx0, (float)(lane - 32));
    float s0, c0; sincosf(__fmul_rn(TPI32, t0), &s0, &c0);
    float t1 = __fmul_rn(hx1, (float)(lane - 32));
    float s1, c1; sincosf(__fmul_rn(TPI32, t1), &s1, &c1);
    float t0x = __fmul_rn(hx0, 32.0f);
    float s0x, c0x; sincosf(__fmul_rn(TPI32, t0x), &s0x, &c0x);
    float t1x = __fmul_rn(hx1, 32.0f);
    float s1x, c1x; sincosf(__fmul_rn(TPI32, t1x), &s1x, &c1x);
    double e0r = (double)c0, e0i = (double)s0;
    double e1r = (double)c1, e1i = (double)s1;
    double gr = 0.0, gi = 0.0;
    for (int a = 0; a < 64; ++a){
      double er = __shfl(e0r, a, 64);
      double ei = __shfl(e0i, a, 64);
      double fr = fbRe[a * 65 + lane];
      double fi = fbIm[a * 65 + lane];
      gr += fr * er - fi * ei;
      gi += fr * ei + fi * er;
    }
    {
      double fr = fbRe[64 * 65 + lane], fi = fbIm[64 * 65 + lane];
      gr += fr * (double)c0x - fi * (double)s0x;
      gi += fr * (double)s0x + fi * (double)c0x;
    }
    double contrib = gr * e1r - gi * e1i;
    {
      double fr = fbRe[lane * 65 + 64], fi = fbIm[lane * 65 + 64];
      double ur = fr * e0r - fi * e0i;
      double ui = fr * e0i + fi * e0r;
      contrib += ur * (double)c1x - ui * (double)s1x;
      if (lane == 0){
        double fr2 = fbRe[64 * 65 + 64], fi2 = fbIm[64 * 65 + 64];
        double vr = fr2 * (double)c0x - fi2 * (double)s0x;
        double vi = fr2 * (double)s0x + fi2 * (double)c0x;
        contrib += vr * (double)c1x - vi * (double)s1x;
      }
    }
    for (int off = 32; off; off >>= 1) contrib += __shfl_xor(contrib, off, 64);
    if (lane == 0) out[n] = (float)contrib;
  }
}

extern "C" void kernel_launch(void* const* d_in, const int* in_sizes, int n_in,
                              void* d_out, int out_size, void* d_ws, size_t ws_size,
                              hipStream_t stream){
  const float* x = (const float*)d_in[0];
  const float* y = (const float*)d_in[1];
  const float* xnew = (const float*)d_in[2];
  float* wsf = (float*)d_ws;
  double* wsd = (double*)d_ws;
  float* out = (float*)d_out;
  unsigned* mm = (unsigned*)(wsf + 4);

  k_init<<<1, 64, 0, stream>>>(mm);
  k_minmax<<<256, 256, 0, stream>>>(x, xnew, mm);
  k_setup<<<1, 256, 0, stream>>>(wsf);
  k_vfk<<<dim3(NCHUNK, 8), 256, 0, stream>>>(x, y, wsf, wsd + D_VPART, wsd + D_FKPART);
  k_reduce_v<<<33, 256, 0, stream>>>(wsd, wsf);
  k_reduce_fk<<<9, 256, 0, stream>>>(wsd, wsf);
  k_vhat<<<129, 192, 0, stream>>>(wsf);
  k_cg_init<<<17, 256, 0, stream>>>(wsf);
  k_pair0<<<1, 256, 0, stream>>>(wsf);
  for (int it = 0; it < CGITERS; ++it){
    k_wfft<<<129, 192, 0, stream>>>(wsf);
    k_ifft<<<65, 192, 0, stream>>>(wsf);
    k_cgstep<<<1, 256, 0, stream>>>(wsf);
  }
  k_predict<<<256, 256, 0, stream>>>(xnew, wsf, out);
}